// Round 4
// baseline (445.136 us; speedup 1.0000x reference)
//
#include <hip/hip_runtime.h>

// Sparse 2-hop GCN slice: output depends only on h2[tgt], tgt = argmax(mut_mask).
// R8: FULL FUSION. 2 dispatches:
//   kinit (tiny: counters, hash=-1, h2/f2pre zero, tgt argmax, is64)
//   kmega (512 blocks x 256 = 2 blocks/CU guaranteed co-resident; spin-join phases):
//     A: col scan -> wscol + L1 edges; blocks 0..31 warm tail weights into L2/L3;
//        blocks 504..511 precompute C = Wh1[256:480]^T feat_aa_pe
//     J1 | per-block LDS dedup l1r -> s1 (identical in every block; replaces slot[])
//     B: int4 scan: S1 membership (17-entry LDS list) -> L2 edges; S2 -> global hash
//     J2 | C: int4 scan with hash in LDS -> deg atomics       J3 (blocks >=32 exit)
//     tail on blocks 0..31 (R7 ktail stages + 3 small joins): slots->h2 | W2->z |
//        Wh1/Wh2->f2pre | block0 out.  No N-sized workspace arrays touched.

#define SCAP   512      // cap on |S1|; expected ~17
#define L1CAP  512      // cap on edges into tgt; expected ~17
#define L2CAP  16384    // cap on edges into S1; expected ~300
#define HID    256
#define INDIM  128
#define HSZ    4096     // deg-needed hash (power of 2; ~300 entries expected)
#define NBLK   512      // kmega grid: 2 blocks/CU
#define NTB    32       // tail-participating blocks

struct WsPtrs {
  int* cnt;     // [0]=n1 [2]=n2 [3]=is64 [4]=tgt [8..13]=join ctrs [15]=warm dummy
  float* deg;   // [N] lazily initialized via hash insert
  int* hash;    // [HSZ] open-addressing set of deg-needed nodes (-1 empty)
  int* l1r; float* l1w;            // edges into tgt
  int* l2r; int* l2s; float* l2w;  // edges into S1
  int* wscol;   // [E] col as int32
  float* h2;    // [HID]
  float* C;     // [512] aa/pos part of head layer 1
  float* z;     // [256]
  float* f2pre; // [128]
};

// K1: counters + hash clear + h2/f2pre zero + argmax(one-hot) + is64 detect
__global__ void kinit(WsPtrs w, const int* eiraw, const float* mask, int N, int E) {
  int g = blockIdx.x * blockDim.x + threadIdx.x;
  int gs = gridDim.x * blockDim.x;
  for (int j = g; j < N; j += gs)
    if (mask[j] > 0.f) w.cnt[4] = j;   // one-hot: exactly one thread fires
  for (int j = g; j < HSZ; j += gs) w.hash[j] = -1;
  if (g < HID) w.h2[g] = 0.f;
  if (g < 128) w.f2pre[g] = 0.f;
  if (g < 3) w.cnt[g] = 0;
  if (g >= 8 && g < 14) w.cnt[g] = 0;
  if (g == 3) {
    int bad = 0;
    long step = E / 20; if (step < 1) step = 1;
    #pragma unroll
    for (int j = 1; j <= 16; ++j) {
      long idx = (long)j * step;
      if (idx < E) bad |= (eiraw[2 * idx + 1] != 0);  // ids < 2^31 -> hi word 0
    }
    w.cnt[3] = bad ? 0 : 1;
  }
}

// open-address insert; winner lazily inits deg[u]=1.0 (self-loop weight)
__device__ __forceinline__ void hins(WsPtrs& w, int u) {
  unsigned h = ((unsigned)u * 2654435761u) >> 20;   // 12-bit slot
  for (;;) {
    int cur = __hip_atomic_load(&w.hash[h], __ATOMIC_RELAXED, __HIP_MEMORY_SCOPE_AGENT);
    if (cur == u) return;
    if (cur == -1) {
      int old = atomicCAS(&w.hash[h], -1, u);
      if (old == -1) { w.deg[u] = 1.0f; return; }
      if (old == u) return;
    }
    h = (h + 1) & (HSZ - 1);
  }
}

__device__ __forceinline__ bool hfind(const int* hS, int u) {
  unsigned h = ((unsigned)u * 2654435761u) >> 20;
  for (;;) {
    int cur = hS[h];
    if (cur == u) return true;
    if (cur == -1) return false;
    h = (h + 1) & (HSZ - 1);
  }
}

// device-scope spin-join: each block signals once, thread 0 polls to target.
__device__ __forceinline__ void join(int* ctr, int tid, int target) {
  __threadfence();
  __syncthreads();
  if (tid == 0) {
    __hip_atomic_fetch_add(ctr, 1, __ATOMIC_RELEASE, __HIP_MEMORY_SCOPE_AGENT);
    while (__hip_atomic_load(ctr, __ATOMIC_ACQUIRE, __HIP_MEMORY_SCOPE_AGENT) < target)
      __builtin_amdgcn_s_sleep(4);
  }
  __syncthreads();
}

__device__ __forceinline__ float warmf4(const float* base, int nf4, int tid) {
  const float4* p = (const float4*)base;
  float a = 0.f;
  for (int i = tid; i < nf4; i += 256) { float4 v = p[i]; a += v.x + v.y + v.z + v.w; }
  return a;
}

__global__ void __launch_bounds__(256) kmega(
    WsPtrs w, const int* eiraw, const float* ew,
    const float* x, const float* W1, const float* b1,
    const float* W2, const float* b2, const float* mask,
    const int* wtI_, const int* mutI_, const float* aa, const float* pemb,
    const float* Wh1, const float* bh1, const float* Wh2, const float* bh2,
    const float* Wh3, const float* bh3, float* out, int E) {
  __shared__ int   l1rS[L1CAP];
  __shared__ float l1wS[L1CAP];
  __shared__ int   s1sL[SCAP];
  __shared__ int   hS[HSZ];        // 16 KB
  __shared__ float xs[2][INDIM];
  __shared__ float buf[256];
  __shared__ float pp[256];
  __shared__ float f1L[16];
  __shared__ int   nsS;

  int tid = threadIdx.x, bid = blockIdx.x;
  const int tgt = w.cnt[4];
  const bool is64 = w.cnt[3] != 0;
  const long long* ell = (const long long*)eiraw;
  int g = bid * 256 + tid;
  const int gs = NBLK * 256;

  // ---------------- phase A: col scan -> wscol + L1 edges ----------------
  for (long e = g; e < E; e += gs) {
    int c = is64 ? (int)ell[(long)E + e] : eiraw[(long)E + e];
    w.wscol[e] = c;
    if (c == tgt) {
      int r = is64 ? (int)ell[e] : eiraw[e];
      int i1 = atomicAdd(&w.cnt[0], 1);
      if (i1 < L1CAP) { w.l1r[i1] = r; w.l1w[i1] = ew[e]; }
    }
  }
  if (g == 0) {  // tgt's self loop (weight 1.0)
    int i1 = atomicAdd(&w.cnt[0], 1);
    if (i1 < L1CAP) { w.l1r[i1] = tgt; w.l1w[i1] = 1.0f; }
  }
  if (bid < NTB) {   // warm tail weights into this block's L2 + shared L3
    float wa = warmf4(W1  + bid * 1024, 256, tid)    //  32768 floats total
             + warmf4(W2  + bid * 2048, 512, tid)    //  65536
             + warmf4(Wh1 + bid * 4096, 1024, tid)   // rows 0..255 = 131072
             + warmf4(Wh2 + bid * 2048, 512, tid);   //  65536
    if (wa == 1.2345e38f) w.cnt[15] = 1;             // keep loads live; never true
  }
  if (bid >= NBLK - 8) {  // C = Wh1[256:480]^T feat_aa_pe (64 outputs/block)
    int b8 = bid - (NBLK - 8);
    int wtI = wtI_[0], mutI = mutI_[0];  // small non-negative; low word ok i32/i64
    if (tid < 64) {
      float a = aa[wtI * 64 + tid], b = aa[mutI * 64 + tid];
      buf[tid] = a; buf[64 + tid] = b; buf[128 + tid] = b - a;
    }
    int pos = tgt > 511 ? 511 : tgt;
    if (tid < 32) buf[192 + tid] = pemb[pos * 32 + tid];
    __syncthreads();
    int o = b8 * 64 + (tid & 63), js = tid >> 6;     // 4 j-slices x 56
    float v = 0.f;
    for (int j = js * 56; j < js * 56 + 56; ++j)
      v += buf[j] * Wh1[(256 + j) * 512 + o];
    pp[tid] = v;
    __syncthreads();
    if (tid < 64)
      w.C[b8 * 64 + tid] = pp[tid] + pp[64 + tid] + pp[128 + tid] + pp[192 + tid];
  }
  join(&w.cnt[8], tid, NBLK);

  // ---- per-block dedup of l1r -> identical s1 list in every block's LDS ----
  int n1 = __hip_atomic_load(&w.cnt[0], __ATOMIC_RELAXED, __HIP_MEMORY_SCOPE_AGENT);
  if (n1 > L1CAP) n1 = L1CAP;
  for (int i = tid; i < n1; i += 256) { l1rS[i] = w.l1r[i]; l1wS[i] = w.l1w[i]; }
  __syncthreads();
  if (tid == 0) {
    int ns = 0;
    for (int i = 0; i < n1; ++i) {
      int v = l1rS[i]; bool seen = false;
      for (int j = 0; j < ns; ++j) if (s1sL[j] == v) { seen = true; break; }
      if (!seen && ns < SCAP) s1sL[ns++] = v;
    }
    nsS = ns;
  }
  __syncthreads();
  int ns = nsS;
  if (bid == 0 && tid < ns) {   // seed: S1 self-loop l2 edges + hash inserts
    int v = s1sL[tid];
    hins(w, v);
    int idx = atomicAdd(&w.cnt[2], 1);
    if (idx < L2CAP) { w.l2r[idx] = v; w.l2s[idx] = tid; w.l2w[idx] = 1.0f; }
  }

  // ---------------- phase B: L2 edges into S1 + S2 hash inserts ----------------
  const int4* c4 = (const int4*)w.wscol;
  int nv = E >> 2;
  for (int j2 = g; j2 < nv; j2 += gs) {
    int4 vv = c4[j2];
    #pragma unroll
    for (int t = 0; t < 4; ++t) {
      int c = (t == 0) ? vv.x : (t == 1) ? vv.y : (t == 2) ? vv.z : vv.w;
      int s = -1;
      for (int j = 0; j < ns; ++j) if (s1sL[j] == c) { s = j; break; }
      if (s >= 0) {
        long e = 4L * j2 + t;
        int r = is64 ? (int)ell[e] : eiraw[e];
        int idx = atomicAdd(&w.cnt[2], 1);
        if (idx < L2CAP) { w.l2r[idx] = r; w.l2s[idx] = s; w.l2w[idx] = ew[e]; }
        hins(w, r);
      }
    }
  }
  for (long e = 4L * nv + g; e < E; e += gs) {
    int c = w.wscol[e];
    int s = -1;
    for (int j = 0; j < ns; ++j) if (s1sL[j] == c) { s = j; break; }
    if (s >= 0) {
      int r = is64 ? (int)ell[e] : eiraw[e];
      int idx = atomicAdd(&w.cnt[2], 1);
      if (idx < L2CAP) { w.l2r[idx] = r; w.l2s[idx] = s; w.l2w[idx] = ew[e]; }
      hins(w, r);
    }
  }
  join(&w.cnt[9], tid, NBLK);

  // ---------------- phase C: deg atomics (hash in LDS) ----------------
  for (int j = tid; j < HSZ; j += 256) hS[j] = w.hash[j];
  __syncthreads();
  for (int j2 = g; j2 < nv; j2 += gs) {
    int4 vv = c4[j2];
    #pragma unroll
    for (int t = 0; t < 4; ++t) {
      int c = (t == 0) ? vv.x : (t == 1) ? vv.y : (t == 2) ? vv.z : vv.w;
      if (hfind(hS, c)) atomicAdd(&w.deg[c], ew[4L * j2 + t]);
    }
  }
  for (long e = 4L * nv + g; e < E; e += gs) {
    int c = w.wscol[e];
    if (hfind(hS, c)) atomicAdd(&w.deg[c], ew[e]);
  }
  join(&w.cnt[10], tid, NBLK);
  if (bid >= NTB) return;

  // ---------------- tail stage 0: slots -> h2 ----------------
  int n2 = __hip_atomic_load(&w.cnt[2], __ATOMIC_RELAXED, __HIP_MEMORY_SCOPE_AGENT);
  if (n2 > L2CAP) n2 = L2CAP;
  float dti = rsqrtf(w.deg[tgt]);
  int grp = tid >> 7, lane = tid & 127;
  for (int s = bid; s < ns; s += NTB) {
    int v = s1sL[s];
    float dv = w.deg[v], dvi = rsqrtf(dv);
    ((float*)xs)[tid] = 0.f;
    __syncthreads();
    for (int i = grp; i < n2; i += 2) {
      if (w.l2s[i] == s) {
        int r = w.l2r[i];
        float nrm = rsqrtf(w.deg[r]) * w.l2w[i] * dvi;
        xs[grp][lane] += nrm * x[(long)r * INDIM + lane];
      }
    }
    __syncthreads();
    float h = b1[tid];
    #pragma unroll 8
    for (int k = 0; k < INDIM; ++k) h += (xs[0][k] + xs[1][k]) * W1[k * HID + tid];
    float wsum = 0.f;
    for (int i = 0; i < n1; ++i) if (l1rS[i] == v) wsum += l1wS[i];
    atomicAdd(&w.h2[tid], dvi * wsum * dti * fmaxf(h, 0.f));
    __syncthreads();
  }
  join(&w.cnt[11], tid, NTB);

  // ---------------- tail stage A: z = relu(h2 @ W2 + b2) * mask[tgt] ----------------
  if (bid < 16) {
    buf[tid] = __hip_atomic_load(&w.h2[tid], __ATOMIC_RELAXED, __HIP_MEMORY_SCOPE_AGENT);
    __syncthreads();
    int o0 = bid * 16, o = o0 + (tid & 15), ks = tid >> 4;
    float v = 0.f;
    #pragma unroll 4
    for (int k = ks * 16; k < ks * 16 + 16; ++k) v += buf[k] * W2[k * HID + o];
    pp[tid] = v;
    __syncthreads();
    if (tid < 16) {
      float zz = b2[o0 + tid];
      for (int s2 = 0; s2 < 16; ++s2) zz += pp[s2 * 16 + tid];
      w.z[o0 + tid] = fmaxf(zz, 0.f) * mask[tgt];
    }
  }
  join(&w.cnt[12], tid, NTB);

  // ---------------- tail stage B: f1 slice + f2pre atomics ----------------
  buf[tid] = __hip_atomic_load(&w.z[tid], __ATOMIC_RELAXED, __HIP_MEMORY_SCOPE_AGENT);
  __syncthreads();
  {
    int o0 = bid * 16, o = o0 + (tid & 15), ks = tid >> 4;
    float v = 0.f;
    #pragma unroll 4
    for (int k = ks * 16; k < ks * 16 + 16; ++k) v += buf[k] * Wh1[k * 512 + o];
    pp[tid] = v;
    __syncthreads();
    if (tid < 16) {
      float v2 = w.C[o0 + tid] + bh1[o0 + tid];
      for (int s2 = 0; s2 < 16; ++s2) v2 += pp[s2 * 16 + tid];
      f1L[tid] = fmaxf(v2, 0.f);
    }
    __syncthreads();
    if (tid < 128) {
      float v3 = 0.f;
      #pragma unroll
      for (int j = 0; j < 16; ++j) v3 += f1L[j] * Wh2[(o0 + j) * 128 + tid];
      atomicAdd(&w.f2pre[tid], v3);
    }
  }
  __threadfence();
  __syncthreads();
  if (tid == 0)
    __hip_atomic_fetch_add(&w.cnt[13], 1, __ATOMIC_RELEASE, __HIP_MEMORY_SCOPE_AGENT);
  if (bid != 0) return;
  if (tid == 0)
    while (__hip_atomic_load(&w.cnt[13], __ATOMIC_ACQUIRE,
                             __HIP_MEMORY_SCOPE_AGENT) < NTB)
      __builtin_amdgcn_s_sleep(4);
  __syncthreads();

  // ---------------- tail stage C: out ----------------
  if (tid < 128)
    pp[tid] = fmaxf(__hip_atomic_load(&w.f2pre[tid], __ATOMIC_RELAXED,
                                      __HIP_MEMORY_SCOPE_AGENT) + bh2[tid], 0.f)
              * Wh3[tid];
  __syncthreads();
  if (tid == 0) {
    float s = bh3[0];
    for (int k = 0; k < 128; ++k) s += pp[k];
    out[0] = s;
  }
}

extern "C" void kernel_launch(void* const* d_in, const int* in_sizes, int n_in,
                              void* d_out, int out_size, void* d_ws, size_t ws_size,
                              hipStream_t stream) {
  const float* x    = (const float*)d_in[0];
  const int*   ei   = (const int*)d_in[1];
  const float* ew   = (const float*)d_in[2];
  const float* mask = (const float*)d_in[3];
  const int*   wtI  = (const int*)d_in[4];
  const int*   mutI = (const int*)d_in[5];
  const float* W1   = (const float*)d_in[6];
  const float* b1   = (const float*)d_in[7];
  const float* W2   = (const float*)d_in[8];
  const float* b2   = (const float*)d_in[9];
  const float* aa   = (const float*)d_in[10];
  const float* pemb = (const float*)d_in[11];
  const float* Wh1  = (const float*)d_in[12];
  const float* bh1  = (const float*)d_in[13];
  const float* Wh2  = (const float*)d_in[14];
  const float* bh2  = (const float*)d_in[15];
  const float* Wh3  = (const float*)d_in[16];
  const float* bh3  = (const float*)d_in[17];
  float* out = (float*)d_out;
  const int N = in_sizes[3];   // mut_mask length
  const int E = in_sizes[2];   // edge_weight length

  char* q = (char*)d_ws;
  auto take = [&](size_t bytes) -> char* {
    char* r = q; q += (bytes + 255) & ~(size_t)255; return r;
  };
  WsPtrs w;
  w.cnt   = (int*)take(64);
  w.deg   = (float*)take((size_t)N * 4);
  w.hash  = (int*)take(HSZ * 4);
  w.l1r   = (int*)take(L1CAP * 4);
  w.l1w   = (float*)take(L1CAP * 4);
  w.l2r   = (int*)take(L2CAP * 4);
  w.l2s   = (int*)take(L2CAP * 4);
  w.l2w   = (float*)take(L2CAP * 4);
  w.wscol = (int*)take((size_t)E * 4);
  w.h2    = (float*)take(HID * 4);
  w.C     = (float*)take(512 * 4);
  w.z     = (float*)take(256 * 4);
  w.f2pre = (float*)take(128 * 4);

  kinit <<<64, 256, 0, stream>>>(w, ei, mask, N, E);
  kmega <<<NBLK, 256, 0, stream>>>(w, ei, ew, x, W1, b1, W2, b2, mask, wtI, mutI,
                                   aa, pemb, Wh1, bh1, Wh2, bh2, Wh3, bh3, out, E);
}

// Round 5
// 259.889 us; speedup vs baseline: 1.7128x; 1.7128x over previous
//
#include <hip/hip_runtime.h>

// Sparse 2-hop GCN slice: output depends only on h2[tgt], tgt = argmax(mut_mask).
// R9: 3 dispatches. Lessons: grid-wide joins cost ~65us at 512 blocks (R8), cheap
// at 32 (R7); big scans need full occupancy (separate dispatches).
//   kinit  (64 blk: hash=-1, counters, h2/f2pre zero, argmax, is64)   ~4us
//   kpassA (2048 scan blk: col->wscol + L1 edges; +8 blk C-precompute;
//           +8 blk warm W1/W2/Wh1[0:256]/Wh2 into L3)                 ~20us
//   ktail  (64 blk: LDS dedup->s1 + bitset; B-scan wscol->l2+hash; join64;
//           bitset|=hash; C-scan (L2-hit re-read)->deg; join64;
//           tail stages 0/A/B/C with small joins -- R7-proven shapes)
// No N-sized workspace arrays. Hash/bitset false-positive-safe for any N.

#define SCAP   512      // cap on |S1|; expected ~17
#define L1CAP  512      // cap on edges into tgt; expected ~17
#define L2CAP  16384    // cap on edges into S1; expected ~300
#define HID    256
#define INDIM  128
#define HSZ    4096     // deg-needed hash (power of 2; ~320 entries expected)
#define BITW   4096     // LDS bitset words (131072 bits, power of 2)
#define NSCAN  2048     // scanning blocks in kpassA
#define NTT    64       // ktail grid
#define NTB    32       // tail-stage-participating blocks

struct WsPtrs {
  int* cnt;     // [0]=n1 [2]=n2 [3]=is64 [4]=tgt [8..12]=join ctrs [15]=dummy
  float* deg;   // [N] lazily initialized via hash insert
  int* hash;    // [HSZ] open-addressing set of deg-needed nodes (-1 empty)
  int* l1r; float* l1w;            // edges into tgt
  int* l2r; int* l2s; float* l2w;  // edges into S1
  int* wscol;   // [E] col as int32
  float* h2;    // [HID]
  float* C;     // [512] aa/pos part of head layer 1
  float* z;     // [256]
  float* f2pre; // [128]
};

// K1: counters + hash clear + h2/f2pre zero + argmax(one-hot) + is64 detect
__global__ void kinit(WsPtrs w, const int* eiraw, const float* mask, int N, int E) {
  int g = blockIdx.x * blockDim.x + threadIdx.x;
  int gs = gridDim.x * blockDim.x;
  for (int j = g; j < N; j += gs)
    if (mask[j] > 0.f) w.cnt[4] = j;   // one-hot: exactly one thread fires
  for (int j = g; j < HSZ; j += gs) w.hash[j] = -1;
  if (g < HID) w.h2[g] = 0.f;
  if (g < 128) w.f2pre[g] = 0.f;
  if (g < 3) w.cnt[g] = 0;
  if (g >= 8 && g < 16) w.cnt[g] = 0;
  if (g == 3) {
    int bad = 0;
    long step = E / 20; if (step < 1) step = 1;
    #pragma unroll
    for (int j = 1; j <= 16; ++j) {
      long idx = (long)j * step;
      if (idx < E) bad |= (eiraw[2 * idx + 1] != 0);  // ids < 2^31 -> hi word 0
    }
    w.cnt[3] = bad ? 0 : 1;
  }
}

// open-address insert; winner lazily inits deg[u]=1.0 (self-loop weight)
__device__ __forceinline__ void hins(WsPtrs& w, int u) {
  unsigned h = ((unsigned)u * 2654435761u) >> 20;   // 12-bit slot
  for (;;) {
    int cur = __hip_atomic_load(&w.hash[h], __ATOMIC_RELAXED, __HIP_MEMORY_SCOPE_AGENT);
    if (cur == u) return;
    if (cur == -1) {
      int old = atomicCAS(&w.hash[h], -1, u);
      if (old == -1) { w.deg[u] = 1.0f; return; }
      if (old == u) return;
    }
    h = (h + 1) & (HSZ - 1);
  }
}

// device-scope spin-join: each block signals once, thread 0 polls to target.
__device__ __forceinline__ void join(int* ctr, int tid, int target) {
  __threadfence();
  __syncthreads();
  if (tid == 0) {
    __hip_atomic_fetch_add(ctr, 1, __ATOMIC_RELEASE, __HIP_MEMORY_SCOPE_AGENT);
    while (__hip_atomic_load(ctr, __ATOMIC_ACQUIRE, __HIP_MEMORY_SCOPE_AGENT) < target)
      __builtin_amdgcn_s_sleep(4);
  }
  __syncthreads();
}

__device__ __forceinline__ float warmf4(const float* base, int nf4, int tid) {
  const float4* p = (const float4*)base;
  float a = 0.f;
  for (int i = tid; i < nf4; i += 256) { float4 v = p[i]; a += v.x + v.y + v.z + v.w; }
  return a;
}

// K2: scan col -> wscol + L1 edges. Extra blocks: C-precompute + L3 weight warm.
__global__ void kpassA(WsPtrs w, const int* eiraw, const float* ew,
                       const int* wtI_, const int* mutI_,
                       const float* aa, const float* pemb, const float* Wh1,
                       const float* W1, const float* W2, const float* Wh2, int E) {
  if (blockIdx.x >= NSCAN + 8) {          // 8 warm blocks: stream 1.2MB into L3
    int b8 = blockIdx.x - (NSCAN + 8);
    int tid = threadIdx.x;
    float wa = warmf4(W1  + b8 * 4096, 1024, tid)     //  32768 floats total
             + warmf4(W2  + b8 * 8192, 2048, tid)     //  65536
             + warmf4(Wh1 + b8 * 16384, 4096, tid)    // rows 0..255 = 131072
             + warmf4(Wh2 + b8 * 8192, 2048, tid);    //  65536
    if (wa == 1.2345e38f) w.cnt[15] = 1;  // keep loads live; never true
    return;
  }
  if (blockIdx.x >= NSCAN) {              // C = Wh1[256:480]^T feat_aa_pe
    __shared__ float fe[224];
    __shared__ float red[256];
    int b8 = blockIdx.x - NSCAN;          // 0..7, 64 outputs each
    int t = threadIdx.x;
    int wtI = wtI_[0], mutI = mutI_[0];   // small non-negative; low word ok i32/i64
    if (t < 64) {
      float a = aa[wtI * 64 + t], b = aa[mutI * 64 + t];
      fe[t] = a; fe[64 + t] = b; fe[128 + t] = b - a;
    }
    int tgt = w.cnt[4];
    int pos = tgt > 511 ? 511 : tgt;
    if (t < 32) fe[192 + t] = pemb[pos * 32 + t];
    __syncthreads();
    int o = b8 * 64 + (t & 63), js = t >> 6;  // 4 j-slices x 56
    float v = 0.f;
    for (int j = js * 56; j < js * 56 + 56; ++j)
      v += fe[j] * Wh1[(256 + j) * 512 + o];
    red[t] = v;
    __syncthreads();
    if (t < 64) w.C[b8 * 64 + t] = red[t] + red[64 + t] + red[128 + t] + red[192 + t];
    return;
  }
  const int tgt = w.cnt[4];
  const bool is64 = w.cnt[3] != 0;
  const long long* ell = (const long long*)eiraw;
  int g = blockIdx.x * blockDim.x + threadIdx.x;
  const int gs = NSCAN * 256;
  for (long e = g; e < E; e += gs) {
    int c = is64 ? (int)ell[(long)E + e] : eiraw[(long)E + e];
    w.wscol[e] = c;
    if (c == tgt) {
      int r = is64 ? (int)ell[e] : eiraw[e];
      int i1 = atomicAdd(&w.cnt[0], 1);
      if (i1 < L1CAP) { w.l1r[i1] = r; w.l1w[i1] = ew[e]; }
    }
  }
  if (g == 0) {  // tgt's self loop (weight 1.0)
    int i1 = atomicAdd(&w.cnt[0], 1);
    if (i1 < L1CAP) { w.l1r[i1] = tgt; w.l1w[i1] = 1.0f; }
  }
}

// K3: 64 blocks. dedup->s1+bitset | B-scan -> l2+hash | join | bitset|=hash |
// C-scan -> deg | join | tail stages (R7 shapes) with small joins.
__global__ void __launch_bounds__(256) ktail(
    WsPtrs w, const int* eiraw, const float* ew,
    const float* x, const float* W1, const float* b1,
    const float* W2, const float* b2, const float* mask,
    const float* Wh1, const float* bh1, const float* Wh2, const float* bh2,
    const float* Wh3, const float* bh3, float* out, int E) {
  __shared__ int      l1rS[L1CAP];
  __shared__ float    l1wS[L1CAP];
  __shared__ int      s1sL[SCAP];
  __shared__ unsigned bits[BITW];     // 16 KB membership filter
  __shared__ float    xs[2][INDIM];
  __shared__ float    buf[256];
  __shared__ float    pp[256];
  __shared__ float    f1L[16];
  __shared__ int      nsS;

  int tid = threadIdx.x, bid = blockIdx.x;
  const int tgt = w.cnt[4];
  const bool is64 = w.cnt[3] != 0;
  const long long* ell = (const long long*)eiraw;
  int g = bid * 256 + tid;
  const int gs = NTT * 256;

  int n1 = w.cnt[0]; if (n1 > L1CAP) n1 = L1CAP;
  for (int i = tid; i < n1; i += 256) { l1rS[i] = w.l1r[i]; l1wS[i] = w.l1w[i]; }
  for (int j = tid; j < BITW; j += 256) bits[j] = 0u;
  __syncthreads();
  if (tid == 0) {                     // n1 ~17 -> trivial serial dedup
    int ns = 0;
    for (int i = 0; i < n1; ++i) {
      int v = l1rS[i]; bool seen = false;
      for (int j = 0; j < ns; ++j) if (s1sL[j] == v) { seen = true; break; }
      if (!seen && ns < SCAP) s1sL[ns++] = v;
    }
    nsS = ns;
  }
  __syncthreads();
  int ns = nsS;
  if (tid < ns) {
    unsigned u = (unsigned)s1sL[tid] & (BITW * 32 - 1);
    atomicOr(&bits[u >> 5], 1u << (u & 31));
    if (bid == 0) {                   // seed: S1 hash inserts + self-loop l2 edges
      int v = s1sL[tid];
      hins(w, v);
      int idx = atomicAdd(&w.cnt[2], 1);
      if (idx < L2CAP) { w.l2r[idx] = v; w.l2s[idx] = tid; w.l2w[idx] = 1.0f; }
    }
  }
  __syncthreads();

  // ---------------- B-scan: wscol -> l2 edges + hash inserts ----------------
  const int4* c4 = (const int4*)w.wscol;
  int nv = E >> 2;
  for (int j2 = g; j2 < nv; j2 += gs) {
    int4 vv = c4[j2];
    #pragma unroll
    for (int t = 0; t < 4; ++t) {
      int c = (t == 0) ? vv.x : (t == 1) ? vv.y : (t == 2) ? vv.z : vv.w;
      unsigned u = (unsigned)c & (BITW * 32 - 1);
      if (bits[u >> 5] & (1u << (u & 31))) {        // filter (exact when N<=128K)
        int s = -1;
        for (int j = 0; j < ns; ++j) if (s1sL[j] == c) { s = j; break; }
        if (s >= 0) {
          long e = 4L * j2 + t;
          int r = is64 ? (int)ell[e] : eiraw[e];
          int idx = atomicAdd(&w.cnt[2], 1);
          if (idx < L2CAP) { w.l2r[idx] = r; w.l2s[idx] = s; w.l2w[idx] = ew[e]; }
          hins(w, r);
        }
      }
    }
  }
  for (long e = 4L * nv + g; e < E; e += gs) {
    int c = w.wscol[e];
    int s = -1;
    for (int j = 0; j < ns; ++j) if (s1sL[j] == c) { s = j; break; }
    if (s >= 0) {
      int r = is64 ? (int)ell[e] : eiraw[e];
      int idx = atomicAdd(&w.cnt[2], 1);
      if (idx < L2CAP) { w.l2r[idx] = r; w.l2s[idx] = s; w.l2w[idx] = ew[e]; }
      hins(w, r);
    }
  }
  join(&w.cnt[8], tid, NTT);

  // ---------------- bitset |= hash; C-scan (L2-hot re-read) -> deg ----------------
  for (int j = tid; j < HSZ; j += 256) {
    int u2 = w.hash[j];
    if (u2 >= 0) {
      unsigned u = (unsigned)u2 & (BITW * 32 - 1);
      atomicOr(&bits[u >> 5], 1u << (u & 31));
    }
  }
  __syncthreads();
  for (int j2 = g; j2 < nv; j2 += gs) {
    int4 vv = c4[j2];
    #pragma unroll
    for (int t = 0; t < 4; ++t) {
      int c = (t == 0) ? vv.x : (t == 1) ? vv.y : (t == 2) ? vv.z : vv.w;
      unsigned u = (unsigned)c & (BITW * 32 - 1);
      if (bits[u >> 5] & (1u << (u & 31)))          // FP at N>128K: harmless extra add
        atomicAdd(&w.deg[c], ew[4L * j2 + t]);
    }
  }
  for (long e = 4L * nv + g; e < E; e += gs) {
    int c = w.wscol[e];
    unsigned u = (unsigned)c & (BITW * 32 - 1);
    if (bits[u >> 5] & (1u << (u & 31))) atomicAdd(&w.deg[c], ew[e]);
  }
  join(&w.cnt[9], tid, NTT);

  // ---------------- tail stage 0: slots -> h2 ----------------
  int n2 = __hip_atomic_load(&w.cnt[2], __ATOMIC_RELAXED, __HIP_MEMORY_SCOPE_AGENT);
  if (n2 > L2CAP) n2 = L2CAP;
  float dti = rsqrtf(w.deg[tgt]);
  int grp = tid >> 7, lane = tid & 127;
  for (int s = bid; s < ns; s += NTT) {
    int v = s1sL[s];
    float dv = w.deg[v], dvi = rsqrtf(dv);
    ((float*)xs)[tid] = 0.f;
    __syncthreads();
    for (int i = grp; i < n2; i += 2) {
      if (w.l2s[i] == s) {
        int r = w.l2r[i];
        float nrm = rsqrtf(w.deg[r]) * w.l2w[i] * dvi;
        xs[grp][lane] += nrm * x[(long)r * INDIM + lane];
      }
    }
    __syncthreads();
    float h = b1[tid];
    #pragma unroll 8
    for (int k = 0; k < INDIM; ++k) h += (xs[0][k] + xs[1][k]) * W1[k * HID + tid];
    float wsum = 0.f;
    for (int i = 0; i < n1; ++i) if (l1rS[i] == v) wsum += l1wS[i];
    atomicAdd(&w.h2[tid], dvi * wsum * dti * fmaxf(h, 0.f));
    __syncthreads();
  }
  join(&w.cnt[10], tid, NTT);

  // ---------------- tail stage A: z = relu(h2 @ W2 + b2) * mask[tgt] ----------------
  if (bid < 16) {
    buf[tid] = __hip_atomic_load(&w.h2[tid], __ATOMIC_RELAXED, __HIP_MEMORY_SCOPE_AGENT);
    __syncthreads();
    int o0 = bid * 16, o = o0 + (tid & 15), ks = tid >> 4;
    float v = 0.f;
    #pragma unroll 4
    for (int k = ks * 16; k < ks * 16 + 16; ++k) v += buf[k] * W2[k * HID + o];
    pp[tid] = v;
    __syncthreads();
    if (tid < 16) {
      float zz = b2[o0 + tid];
      for (int s2 = 0; s2 < 16; ++s2) zz += pp[s2 * 16 + tid];
      w.z[o0 + tid] = fmaxf(zz, 0.f) * mask[tgt];
    }
  }
  join(&w.cnt[11], tid, NTT);

  // ---------------- tail stage B: f1 slice + f2pre atomics (32 blocks) ----------------
  if (bid < NTB) {
    buf[tid] = __hip_atomic_load(&w.z[tid], __ATOMIC_RELAXED, __HIP_MEMORY_SCOPE_AGENT);
    __syncthreads();
    int o0 = bid * 16, o = o0 + (tid & 15), ks = tid >> 4;
    float v = 0.f;
    #pragma unroll 4
    for (int k = ks * 16; k < ks * 16 + 16; ++k) v += buf[k] * Wh1[k * 512 + o];
    pp[tid] = v;
    __syncthreads();
    if (tid < 16) {
      float v2 = w.C[o0 + tid] + bh1[o0 + tid];
      for (int s2 = 0; s2 < 16; ++s2) v2 += pp[s2 * 16 + tid];
      f1L[tid] = fmaxf(v2, 0.f);
    }
    __syncthreads();
    if (tid < 128) {
      float v3 = 0.f;
      #pragma unroll
      for (int j = 0; j < 16; ++j) v3 += f1L[j] * Wh2[(o0 + j) * 128 + tid];
      atomicAdd(&w.f2pre[tid], v3);
    }
  }
  __threadfence();
  __syncthreads();
  if (tid == 0)
    __hip_atomic_fetch_add(&w.cnt[12], 1, __ATOMIC_RELEASE, __HIP_MEMORY_SCOPE_AGENT);
  if (bid != 0) return;
  if (tid == 0)
    while (__hip_atomic_load(&w.cnt[12], __ATOMIC_ACQUIRE,
                             __HIP_MEMORY_SCOPE_AGENT) < NTT)
      __builtin_amdgcn_s_sleep(4);
  __syncthreads();

  // ---------------- tail stage C: out ----------------
  if (tid < 128)
    pp[tid] = fmaxf(__hip_atomic_load(&w.f2pre[tid], __ATOMIC_RELAXED,
                                      __HIP_MEMORY_SCOPE_AGENT) + bh2[tid], 0.f)
              * Wh3[tid];
  __syncthreads();
  if (tid == 0) {
    float s = bh3[0];
    for (int k = 0; k < 128; ++k) s += pp[k];
    out[0] = s;
  }
}

extern "C" void kernel_launch(void* const* d_in, const int* in_sizes, int n_in,
                              void* d_out, int out_size, void* d_ws, size_t ws_size,
                              hipStream_t stream) {
  const float* x    = (const float*)d_in[0];
  const int*   ei   = (const int*)d_in[1];
  const float* ew   = (const float*)d_in[2];
  const float* mask = (const float*)d_in[3];
  const int*   wtI  = (const int*)d_in[4];
  const int*   mutI = (const int*)d_in[5];
  const float* W1   = (const float*)d_in[6];
  const float* b1   = (const float*)d_in[7];
  const float* W2   = (const float*)d_in[8];
  const float* b2   = (const float*)d_in[9];
  const float* aa   = (const float*)d_in[10];
  const float* pemb = (const float*)d_in[11];
  const float* Wh1  = (const float*)d_in[12];
  const float* bh1  = (const float*)d_in[13];
  const float* Wh2  = (const float*)d_in[14];
  const float* bh2  = (const float*)d_in[15];
  const float* Wh3  = (const float*)d_in[16];
  const float* bh3  = (const float*)d_in[17];
  float* out = (float*)d_out;
  const int N = in_sizes[3];   // mut_mask length
  const int E = in_sizes[2];   // edge_weight length

  char* q = (char*)d_ws;
  auto take = [&](size_t bytes) -> char* {
    char* r = q; q += (bytes + 255) & ~(size_t)255; return r;
  };
  WsPtrs w;
  w.cnt   = (int*)take(64);
  w.deg   = (float*)take((size_t)N * 4);
  w.hash  = (int*)take(HSZ * 4);
  w.l1r   = (int*)take(L1CAP * 4);
  w.l1w   = (float*)take(L1CAP * 4);
  w.l2r   = (int*)take(L2CAP * 4);
  w.l2s   = (int*)take(L2CAP * 4);
  w.l2w   = (float*)take(L2CAP * 4);
  w.wscol = (int*)take((size_t)E * 4);
  w.h2    = (float*)take(HID * 4);
  w.C     = (float*)take(512 * 4);
  w.z     = (float*)take(256 * 4);
  w.f2pre = (float*)take(128 * 4);

  kinit  <<<64, 256, 0, stream>>>(w, ei, mask, N, E);
  kpassA <<<NSCAN + 16, 256, 0, stream>>>(w, ei, ew, wtI, mutI, aa, pemb, Wh1,
                                          W1, W2, Wh2, E);
  ktail  <<<NTT, 256, 0, stream>>>(w, ei, ew, x, W1, b1, W2, b2, mask,
                                   Wh1, bh1, Wh2, bh2, Wh3, bh3, out, E);
}

// Round 6
// 224.280 us; speedup vs baseline: 1.9847x; 1.1588x over previous
//
#include <hip/hip_runtime.h>

// Sparse 2-hop GCN slice: output depends only on h2[tgt], tgt = argmax(mut_mask).
// R10: full-occupancy scans + 2-join tail. Model from R7-R9: dur ~= 100us fixed
// overhead + sum(kernel durs); full-E scans need >=1024 blocks (64-blk scan = 43GB/s
// disaster, R9); joins cheap only at ~32 blocks (R7 vs R8). 5 dispatches:
//   kinit  (64 blk: hash=-1, counters, h2/f2pre zero, argmax, is64)      ~4us
//   kpassA (2048 scan blk: col->wscol + L1 edges; +8 blk C-precompute;
//           +8 blk warm W1/W2/Wh1[0:256]/Wh2 into L3)                    ~25us
//   kpassB (1024 blk: LDS dedup->s1+bitset; wscol int4 scan -> l2 + hash) ~8us
//   kpassC (1024 blk: bitset from hash; wscol+ew scan -> deg atomics)     ~8us
//   ktail  (32 blk, 2 joins: stage0 slots->h2 | join | redundant z/block
//           (W2 L3-warm) -> f1 slice -> f2pre atomics | join | blk0 out)  ~30us
// No N-sized workspace arrays. Bitset/hash false-positive-safe for any N.

#define SCAP   512      // cap on |S1|; expected ~17
#define L1CAP  512      // cap on edges into tgt; expected ~17
#define L2CAP  16384    // cap on edges into S1; expected ~300
#define HID    256
#define INDIM  128
#define HSZ    4096     // deg-needed hash (power of 2; ~320 entries expected)
#define BITW   4096     // LDS bitset words (131072 bits, power of 2)
#define NSCAN  2048     // scanning blocks in kpassA
#define NB     1024     // kpassB/kpassC grids
#define NTB    32       // ktail grid

struct WsPtrs {
  int* cnt;     // [0]=n1 [2]=n2 [3]=is64 [4]=tgt [8..9]=join ctrs [15]=dummy
  float* deg;   // [N] lazily initialized via hash insert
  int* hash;    // [HSZ] open-addressing set of deg-needed nodes (-1 empty)
  int* l1r; float* l1w;            // edges into tgt
  int* l2r; int* l2s; float* l2w;  // edges into S1
  int* wscol;   // [E] col as int32
  float* h2;    // [HID]
  float* C;     // [512] aa/pos part of head layer 1
  float* f2pre; // [128]
};

// K1: counters + hash clear + h2/f2pre zero + argmax(one-hot) + is64 detect
__global__ void kinit(WsPtrs w, const int* eiraw, const float* mask, int N, int E) {
  int g = blockIdx.x * blockDim.x + threadIdx.x;
  int gs = gridDim.x * blockDim.x;
  for (int j = g; j < N; j += gs)
    if (mask[j] > 0.f) w.cnt[4] = j;   // one-hot: exactly one thread fires
  for (int j = g; j < HSZ; j += gs) w.hash[j] = -1;
  if (g < HID) w.h2[g] = 0.f;
  if (g < 128) w.f2pre[g] = 0.f;
  if (g < 3) w.cnt[g] = 0;
  if (g >= 8 && g < 16) w.cnt[g] = 0;
  if (g == 3) {
    int bad = 0;
    long step = E / 20; if (step < 1) step = 1;
    #pragma unroll
    for (int j = 1; j <= 16; ++j) {
      long idx = (long)j * step;
      if (idx < E) bad |= (eiraw[2 * idx + 1] != 0);  // ids < 2^31 -> hi word 0
    }
    w.cnt[3] = bad ? 0 : 1;
  }
}

// open-address insert; winner lazily inits deg[u]=1.0 (self-loop weight)
__device__ __forceinline__ void hins(WsPtrs& w, int u) {
  unsigned h = ((unsigned)u * 2654435761u) >> 20;   // 12-bit slot
  for (;;) {
    int cur = __hip_atomic_load(&w.hash[h], __ATOMIC_RELAXED, __HIP_MEMORY_SCOPE_AGENT);
    if (cur == u) return;
    if (cur == -1) {
      int old = atomicCAS(&w.hash[h], -1, u);
      if (old == -1) { w.deg[u] = 1.0f; return; }
      if (old == u) return;
    }
    h = (h + 1) & (HSZ - 1);
  }
}

// device-scope spin-join: each block signals once, thread 0 polls to target.
__device__ __forceinline__ void join(int* ctr, int tid, int target) {
  __threadfence();
  __syncthreads();
  if (tid == 0) {
    __hip_atomic_fetch_add(ctr, 1, __ATOMIC_RELEASE, __HIP_MEMORY_SCOPE_AGENT);
    while (__hip_atomic_load(ctr, __ATOMIC_ACQUIRE, __HIP_MEMORY_SCOPE_AGENT) < target)
      __builtin_amdgcn_s_sleep(4);
  }
  __syncthreads();
}

__device__ __forceinline__ float warmf4(const float* base, int nf4, int tid) {
  const float4* p = (const float4*)base;
  float a = 0.f;
  for (int i = tid; i < nf4; i += 256) { float4 v = p[i]; a += v.x + v.y + v.z + v.w; }
  return a;
}

// builds the identical dedup'd s1 list in this block's LDS; returns ns
__device__ __forceinline__ int dedup_s1(WsPtrs& w, int n1, int* l1rS, float* l1wS,
                                        int* s1sL, int* nsS, int tid) {
  for (int i = tid; i < n1; i += 256) { l1rS[i] = w.l1r[i]; l1wS[i] = w.l1w[i]; }
  __syncthreads();
  if (tid == 0) {                     // n1 ~17 -> trivial serial dedup
    int ns = 0;
    for (int i = 0; i < n1; ++i) {
      int v = l1rS[i]; bool seen = false;
      for (int j = 0; j < ns; ++j) if (s1sL[j] == v) { seen = true; break; }
      if (!seen && ns < SCAP) s1sL[ns++] = v;
    }
    *nsS = ns;
  }
  __syncthreads();
  return *nsS;
}

// K2: scan col -> wscol + L1 edges. Extra blocks: C-precompute + L3 weight warm.
__global__ void kpassA(WsPtrs w, const int* eiraw, const float* ew,
                       const int* wtI_, const int* mutI_,
                       const float* aa, const float* pemb, const float* Wh1,
                       const float* W1, const float* W2, const float* Wh2, int E) {
  if (blockIdx.x >= NSCAN + 8) {          // 8 warm blocks: stream 1.2MB into L3
    int b8 = blockIdx.x - (NSCAN + 8);
    int tid = threadIdx.x;
    float wa = warmf4(W1  + b8 * 4096, 1024, tid)     //  32768 floats total
             + warmf4(W2  + b8 * 8192, 2048, tid)     //  65536
             + warmf4(Wh1 + b8 * 16384, 4096, tid)    // rows 0..255 = 131072
             + warmf4(Wh2 + b8 * 8192, 2048, tid);    //  65536
    if (wa == 1.2345e38f) w.cnt[15] = 1;  // keep loads live; never true
    return;
  }
  if (blockIdx.x >= NSCAN) {              // C = Wh1[256:480]^T feat_aa_pe
    __shared__ float fe[224];
    __shared__ float red[256];
    int b8 = blockIdx.x - NSCAN;          // 0..7, 64 outputs each
    int t = threadIdx.x;
    int wtI = wtI_[0], mutI = mutI_[0];   // small non-negative; low word ok i32/i64
    if (t < 64) {
      float a = aa[wtI * 64 + t], b = aa[mutI * 64 + t];
      fe[t] = a; fe[64 + t] = b; fe[128 + t] = b - a;
    }
    int tgt = w.cnt[4];
    int pos = tgt > 511 ? 511 : tgt;
    if (t < 32) fe[192 + t] = pemb[pos * 32 + t];
    __syncthreads();
    int o = b8 * 64 + (t & 63), js = t >> 6;  // 4 j-slices x 56
    float v = 0.f;
    for (int j = js * 56; j < js * 56 + 56; ++j)
      v += fe[j] * Wh1[(256 + j) * 512 + o];
    red[t] = v;
    __syncthreads();
    if (t < 64) w.C[b8 * 64 + t] = red[t] + red[64 + t] + red[128 + t] + red[192 + t];
    return;
  }
  const int tgt = w.cnt[4];
  const bool is64 = w.cnt[3] != 0;
  const long long* ell = (const long long*)eiraw;
  int g = blockIdx.x * blockDim.x + threadIdx.x;
  const int gs = NSCAN * 256;
  for (long e = g; e < E; e += gs) {
    int c = is64 ? (int)ell[(long)E + e] : eiraw[(long)E + e];
    w.wscol[e] = c;
    if (c == tgt) {
      int r = is64 ? (int)ell[e] : eiraw[e];
      int i1 = atomicAdd(&w.cnt[0], 1);
      if (i1 < L1CAP) { w.l1r[i1] = r; w.l1w[i1] = ew[e]; }
    }
  }
  if (g == 0) {  // tgt's self loop (weight 1.0)
    int i1 = atomicAdd(&w.cnt[0], 1);
    if (i1 < L1CAP) { w.l1r[i1] = tgt; w.l1w[i1] = 1.0f; }
  }
}

// K3: 1024 blocks: per-block dedup -> s1 + LDS bitset; wscol int4 scan -> l2 + hash
__global__ void kpassB(WsPtrs w, const int* eiraw, const float* ew, int E) {
  __shared__ int      l1rS[L1CAP];
  __shared__ float    l1wS[L1CAP];
  __shared__ int      s1sL[SCAP];
  __shared__ unsigned bits[BITW];     // 16 KB
  __shared__ int      nsS;
  int tid = threadIdx.x;
  const bool is64 = w.cnt[3] != 0;
  const long long* ell = (const long long*)eiraw;
  int n1 = w.cnt[0]; if (n1 > L1CAP) n1 = L1CAP;
  for (int j = tid; j < BITW; j += 256) bits[j] = 0u;
  int ns = dedup_s1(w, n1, l1rS, l1wS, s1sL, &nsS, tid);
  for (int j = tid; j < ns; j += 256) {
    unsigned u = (unsigned)s1sL[j] & (BITW * 32 - 1);
    atomicOr(&bits[u >> 5], 1u << (u & 31));
    if (blockIdx.x == 0) {            // seed: S1 hash inserts + self-loop l2 edges
      int v = s1sL[j];
      hins(w, v);
      int idx = atomicAdd(&w.cnt[2], 1);
      if (idx < L2CAP) { w.l2r[idx] = v; w.l2s[idx] = j; w.l2w[idx] = 1.0f; }
    }
  }
  __syncthreads();
  int g = blockIdx.x * 256 + tid;
  const int gs = NB * 256;
  const int4* c4 = (const int4*)w.wscol;
  int nv = E >> 2;
  for (int j2 = g; j2 < nv; j2 += gs) {
    int4 vv = c4[j2];
    #pragma unroll
    for (int t = 0; t < 4; ++t) {
      int c = (t == 0) ? vv.x : (t == 1) ? vv.y : (t == 2) ? vv.z : vv.w;
      unsigned u = (unsigned)c & (BITW * 32 - 1);
      if (bits[u >> 5] & (1u << (u & 31))) {        // exact when N<=128K
        int s = -1;
        for (int j = 0; j < ns; ++j) if (s1sL[j] == c) { s = j; break; }
        if (s >= 0) {
          long e = 4L * j2 + t;
          int r = is64 ? (int)ell[e] : eiraw[e];
          int idx = atomicAdd(&w.cnt[2], 1);
          if (idx < L2CAP) { w.l2r[idx] = r; w.l2s[idx] = s; w.l2w[idx] = ew[e]; }
          hins(w, r);
        }
      }
    }
  }
  for (long e = 4L * nv + g; e < E; e += gs) {
    int c = w.wscol[e];
    int s = -1;
    for (int j = 0; j < ns; ++j) if (s1sL[j] == c) { s = j; break; }
    if (s >= 0) {
      int r = is64 ? (int)ell[e] : eiraw[e];
      int idx = atomicAdd(&w.cnt[2], 1);
      if (idx < L2CAP) { w.l2r[idx] = r; w.l2s[idx] = s; w.l2w[idx] = ew[e]; }
      hins(w, r);
    }
  }
}

// K4: 1024 blocks: LDS bitset from hash; wscol+ew scan -> deg atomics
__global__ void kpassC(WsPtrs w, const float* ew, int E) {
  __shared__ unsigned bits[BITW];
  int tid = threadIdx.x;
  for (int j = tid; j < BITW; j += 256) bits[j] = 0u;
  __syncthreads();
  for (int j = tid; j < HSZ; j += 256) {
    int u2 = w.hash[j];
    if (u2 >= 0) {
      unsigned u = (unsigned)u2 & (BITW * 32 - 1);
      atomicOr(&bits[u >> 5], 1u << (u & 31));
    }
  }
  __syncthreads();
  int g = blockIdx.x * 256 + tid;
  const int gs = NB * 256;
  const int4* c4 = (const int4*)w.wscol;
  int nv = E >> 2;
  for (int j2 = g; j2 < nv; j2 += gs) {
    int4 vv = c4[j2];
    #pragma unroll
    for (int t = 0; t < 4; ++t) {
      int c = (t == 0) ? vv.x : (t == 1) ? vv.y : (t == 2) ? vv.z : vv.w;
      unsigned u = (unsigned)c & (BITW * 32 - 1);
      if (bits[u >> 5] & (1u << (u & 31)))          // FP at N>128K: harmless extra add
        atomicAdd(&w.deg[c], ew[4L * j2 + t]);
    }
  }
  for (long e = 4L * nv + g; e < E; e += gs) {
    int c = w.wscol[e];
    unsigned u = (unsigned)c & (BITW * 32 - 1);
    if (bits[u >> 5] & (1u << (u & 31))) atomicAdd(&w.deg[c], ew[e]);
  }
}

// K5: 32 blocks, 2 joins. stage0 slots->h2 | join | per-block full z (redundant,
// W2 L3-warm) -> f1 slice -> f2pre atomics | join | block0: out.
__global__ void __launch_bounds__(256) ktail(
    WsPtrs w, const float* x, const float* W1, const float* b1,
    const float* W2, const float* b2, const float* mask,
    const float* Wh1, const float* bh1, const float* Wh2, const float* bh2,
    const float* Wh3, const float* bh3, float* out) {
  __shared__ int   l1rS[L1CAP];
  __shared__ float l1wS[L1CAP];
  __shared__ int   s1sL[SCAP];
  __shared__ int   nsS;
  __shared__ float xs[2][INDIM];
  __shared__ float zL[256];
  __shared__ float pp[256];
  __shared__ float f1L[16];

  int tid = threadIdx.x, bid = blockIdx.x;
  const int tgt = w.cnt[4];
  int n1 = w.cnt[0]; if (n1 > L1CAP) n1 = L1CAP;
  int n2 = w.cnt[2]; if (n2 > L2CAP) n2 = L2CAP;
  int ns = dedup_s1(w, n1, l1rS, l1wS, s1sL, &nsS, tid);
  float dti = rsqrtf(w.deg[tgt]);

  // ---------------- stage 0: slots -> h2 ----------------
  int grp = tid >> 7, lane = tid & 127;
  for (int s = bid; s < ns; s += NTB) {
    int v = s1sL[s];
    float dv = w.deg[v], dvi = rsqrtf(dv);
    ((float*)xs)[tid] = 0.f;
    __syncthreads();
    for (int i = grp; i < n2; i += 2) {
      if (w.l2s[i] == s) {
        int r = w.l2r[i];
        float nrm = rsqrtf(w.deg[r]) * w.l2w[i] * dvi;
        xs[grp][lane] += nrm * x[(long)r * INDIM + lane];
      }
    }
    __syncthreads();
    float h = b1[tid];
    #pragma unroll 8
    for (int k = 0; k < INDIM; ++k) h += (xs[0][k] + xs[1][k]) * W1[k * HID + tid];
    float wsum = 0.f;
    for (int i = 0; i < n1; ++i) if (l1rS[i] == v) wsum += l1wS[i];
    atomicAdd(&w.h2[tid], dvi * wsum * dti * fmaxf(h, 0.f));
    __syncthreads();
  }
  join(&w.cnt[8], tid, NTB);

  // ------ per-block redundant z = relu(h2 @ W2 + b2) * mask[tgt] (W2 L3-warm) ------
  pp[tid] = __hip_atomic_load(&w.h2[tid], __ATOMIC_RELAXED, __HIP_MEMORY_SCOPE_AGENT);
  __syncthreads();
  {
    float v = b2[tid];
    #pragma unroll 8
    for (int k = 0; k < HID; ++k) v += pp[k] * W2[k * HID + tid];
    zL[tid] = fmaxf(v, 0.f) * mask[tgt];
  }
  __syncthreads();

  // ---------------- f1 slice (16 outs/block) + f2pre atomics ----------------
  {
    int o0 = bid * 16, o = o0 + (tid & 15), ks = tid >> 4;
    float v = 0.f;
    #pragma unroll 4
    for (int k = ks * 16; k < ks * 16 + 16; ++k) v += zL[k] * Wh1[k * 512 + o];
    pp[tid] = v;
    __syncthreads();
    if (tid < 16) {
      float v2 = w.C[o0 + tid] + bh1[o0 + tid];
      for (int s2 = 0; s2 < 16; ++s2) v2 += pp[s2 * 16 + tid];
      f1L[tid] = fmaxf(v2, 0.f);
    }
    __syncthreads();
    if (tid < 128) {
      float v3 = 0.f;
      #pragma unroll
      for (int j = 0; j < 16; ++j) v3 += f1L[j] * Wh2[(o0 + j) * 128 + tid];
      atomicAdd(&w.f2pre[tid], v3);
    }
  }
  __threadfence();
  __syncthreads();
  if (tid == 0)
    __hip_atomic_fetch_add(&w.cnt[9], 1, __ATOMIC_RELEASE, __HIP_MEMORY_SCOPE_AGENT);
  if (bid != 0) return;
  if (tid == 0)
    while (__hip_atomic_load(&w.cnt[9], __ATOMIC_ACQUIRE,
                             __HIP_MEMORY_SCOPE_AGENT) < NTB)
      __builtin_amdgcn_s_sleep(4);
  __syncthreads();

  // ---------------- out ----------------
  if (tid < 128)
    pp[tid] = fmaxf(__hip_atomic_load(&w.f2pre[tid], __ATOMIC_RELAXED,
                                      __HIP_MEMORY_SCOPE_AGENT) + bh2[tid], 0.f)
              * Wh3[tid];
  __syncthreads();
  if (tid == 0) {
    float s = bh3[0];
    for (int k = 0; k < 128; ++k) s += pp[k];
    out[0] = s;
  }
}

extern "C" void kernel_launch(void* const* d_in, const int* in_sizes, int n_in,
                              void* d_out, int out_size, void* d_ws, size_t ws_size,
                              hipStream_t stream) {
  const float* x    = (const float*)d_in[0];
  const int*   ei   = (const int*)d_in[1];
  const float* ew   = (const float*)d_in[2];
  const float* mask = (const float*)d_in[3];
  const int*   wtI  = (const int*)d_in[4];
  const int*   mutI = (const int*)d_in[5];
  const float* W1   = (const float*)d_in[6];
  const float* b1   = (const float*)d_in[7];
  const float* W2   = (const float*)d_in[8];
  const float* b2   = (const float*)d_in[9];
  const float* aa   = (const float*)d_in[10];
  const float* pemb = (const float*)d_in[11];
  const float* Wh1  = (const float*)d_in[12];
  const float* bh1  = (const float*)d_in[13];
  const float* Wh2  = (const float*)d_in[14];
  const float* bh2  = (const float*)d_in[15];
  const float* Wh3  = (const float*)d_in[16];
  const float* bh3  = (const float*)d_in[17];
  float* out = (float*)d_out;
  const int N = in_sizes[3];   // mut_mask length
  const int E = in_sizes[2];   // edge_weight length

  char* q = (char*)d_ws;
  auto take = [&](size_t bytes) -> char* {
    char* r = q; q += (bytes + 255) & ~(size_t)255; return r;
  };
  WsPtrs w;
  w.cnt   = (int*)take(64);
  w.deg   = (float*)take((size_t)N * 4);
  w.hash  = (int*)take(HSZ * 4);
  w.l1r   = (int*)take(L1CAP * 4);
  w.l1w   = (float*)take(L1CAP * 4);
  w.l2r   = (int*)take(L2CAP * 4);
  w.l2s   = (int*)take(L2CAP * 4);
  w.l2w   = (float*)take(L2CAP * 4);
  w.wscol = (int*)take((size_t)E * 4);
  w.h2    = (float*)take(HID * 4);
  w.C     = (float*)take(512 * 4);
  w.f2pre = (float*)take(128 * 4);

  kinit  <<<64, 256, 0, stream>>>(w, ei, mask, N, E);
  kpassA <<<NSCAN + 16, 256, 0, stream>>>(w, ei, ew, wtI, mutI, aa, pemb, Wh1,
                                          W1, W2, Wh2, E);
  kpassB <<<NB, 256, 0, stream>>>(w, ei, ew, E);
  kpassC <<<NB, 256, 0, stream>>>(w, ew, E);
  ktail  <<<NTB, 256, 0, stream>>>(w, x, W1, b1, W2, b2, mask,
                                   Wh1, bh1, Wh2, bh2, Wh3, bh3, out);
}

// Round 7
// 203.513 us; speedup vs baseline: 2.1873x; 1.1020x over previous
//
#include <hip/hip_runtime.h>

// Sparse 2-hop GCN slice: output depends only on h2[tgt], tgt = argmax(mut_mask).
// R11: R10 skeleton, ktail dataflow rewritten so every weight matrix is read ONCE
// in aggregate (32 blocks x 8-output slices), edges gathered in parallel.
//   kinit  (64 blk: hash=-1, counters, xsum/f2pre zero, argmax, is64)
//   kpassA (2048 blk vectorized col scan -> wscol + L1; +8 C-precompute; +8 warm)
//   kpassB (1024 blk: dedup->s1+bitset; wscol int4 scan -> l2 + hash)
//   kpassC (1024 blk: bitset from hash; wscol+ew scan -> deg atomics)
//   ktail  (32 blk, 4 joins: 1a edge-gather->xsum | 1b one-pass W1 -> h2 slice |
//           z slice (W2 once) | f1 slice + f2pre atomics | blk0 out)

#define SCAP   512      // cap on |S1|; expected ~17
#define L1CAP  512      // cap on edges into tgt; expected ~17
#define L2CAP  16384    // cap on edges into S1; expected ~300
#define HID    256
#define INDIM  128
#define HSZ    4096     // deg-needed hash (power of 2; ~320 entries expected)
#define BITW   4096     // LDS bitset words (131072 bits, power of 2)
#define NSCAN  2048     // scanning blocks in kpassA
#define NB     1024     // kpassB/kpassC grids
#define NTB    32       // ktail grid

struct WsPtrs {
  int* cnt;     // [0]=n1 [2]=n2 [3]=is64 [4]=tgt [8..11]=join ctrs [15]=dummy
  float* deg;   // [N] lazily initialized via hash insert
  int* hash;    // [HSZ] open-addressing set of deg-needed nodes (-1 empty)
  int* l1r; float* l1w;            // edges into tgt
  int* l2r; int* l2s; float* l2w;  // edges into S1
  int* wscol;   // [E] col as int32
  float* xsum;  // [SCAP*INDIM] per-slot normalized x sums
  float* h2;    // [HID]
  float* C;     // [512] aa/pos part of head layer 1
  float* z;     // [256]
  float* f2pre; // [128]
};

// K1: counters + hash clear + xsum/f2pre zero + argmax(one-hot) + is64 detect
__global__ void kinit(WsPtrs w, const int* eiraw, const float* mask, int N, int E) {
  int g = blockIdx.x * blockDim.x + threadIdx.x;
  int gs = gridDim.x * blockDim.x;
  for (int j = g; j < N; j += gs)
    if (mask[j] > 0.f) w.cnt[4] = j;   // one-hot: exactly one thread fires
  for (int j = g; j < HSZ; j += gs) w.hash[j] = -1;
  float4* xz = (float4*)w.xsum;
  for (int j = g; j < SCAP * INDIM / 4; j += gs) xz[j] = make_float4(0.f, 0.f, 0.f, 0.f);
  if (g < HID) w.h2[g] = 0.f;
  if (g < 128) w.f2pre[g] = 0.f;
  if (g < 3) w.cnt[g] = 0;
  if (g >= 8 && g < 16) w.cnt[g] = 0;
  if (g == 3) {
    int bad = 0;
    long step = E / 20; if (step < 1) step = 1;
    #pragma unroll
    for (int j = 1; j <= 16; ++j) {
      long idx = (long)j * step;
      if (idx < E) bad |= (eiraw[2 * idx + 1] != 0);  // ids < 2^31 -> hi word 0
    }
    w.cnt[3] = bad ? 0 : 1;
  }
}

// open-address insert; winner lazily inits deg[u]=1.0 (self-loop weight)
__device__ __forceinline__ void hins(WsPtrs& w, int u) {
  unsigned h = ((unsigned)u * 2654435761u) >> 20;   // 12-bit slot
  for (;;) {
    int cur = __hip_atomic_load(&w.hash[h], __ATOMIC_RELAXED, __HIP_MEMORY_SCOPE_AGENT);
    if (cur == u) return;
    if (cur == -1) {
      int old = atomicCAS(&w.hash[h], -1, u);
      if (old == -1) { w.deg[u] = 1.0f; return; }
      if (old == u) return;
    }
    h = (h + 1) & (HSZ - 1);
  }
}

// device-scope spin-join: each block signals once, thread 0 polls to target.
__device__ __forceinline__ void join(int* ctr, int tid, int target) {
  __threadfence();
  __syncthreads();
  if (tid == 0) {
    __hip_atomic_fetch_add(ctr, 1, __ATOMIC_RELEASE, __HIP_MEMORY_SCOPE_AGENT);
    while (__hip_atomic_load(ctr, __ATOMIC_ACQUIRE, __HIP_MEMORY_SCOPE_AGENT) < target)
      __builtin_amdgcn_s_sleep(4);
  }
  __syncthreads();
}

__device__ __forceinline__ float warmf4(const float* base, int nf4, int tid) {
  const float4* p = (const float4*)base;
  float a = 0.f;
  for (int i = tid; i < nf4; i += 256) { float4 v = p[i]; a += v.x + v.y + v.z + v.w; }
  return a;
}

// builds the identical dedup'd s1 list in this block's LDS; returns ns
__device__ __forceinline__ int dedup_s1(WsPtrs& w, int n1, int* l1rS, float* l1wS,
                                        int* s1sL, int* nsS, int tid) {
  for (int i = tid; i < n1; i += 256) { l1rS[i] = w.l1r[i]; l1wS[i] = w.l1w[i]; }
  __syncthreads();
  if (tid == 0) {                     // n1 ~17 -> trivial serial dedup
    int ns = 0;
    for (int i = 0; i < n1; ++i) {
      int v = l1rS[i]; bool seen = false;
      for (int j = 0; j < ns; ++j) if (s1sL[j] == v) { seen = true; break; }
      if (!seen && ns < SCAP) s1sL[ns++] = v;
    }
    *nsS = ns;
  }
  __syncthreads();
  return *nsS;
}

// K2: scan col -> wscol + L1 edges (2 edges/iter). Extra blocks: C-precompute + warm.
__global__ void kpassA(WsPtrs w, const int* eiraw, const float* ew,
                       const int* wtI_, const int* mutI_,
                       const float* aa, const float* pemb, const float* Wh1,
                       const float* W1, const float* W2, const float* Wh2, int E) {
  if (blockIdx.x >= NSCAN + 8) {          // 8 warm blocks: stream 1.2MB into L3
    int b8 = blockIdx.x - (NSCAN + 8);
    int tid = threadIdx.x;
    float wa = warmf4(W1  + b8 * 4096, 1024, tid)     //  32768 floats total
             + warmf4(W2  + b8 * 8192, 2048, tid)     //  65536
             + warmf4(Wh1 + b8 * 16384, 4096, tid)    // rows 0..255 = 131072
             + warmf4(Wh2 + b8 * 8192, 2048, tid);    //  65536
    if (wa == 1.2345e38f) w.cnt[15] = 1;  // keep loads live; never true
    return;
  }
  if (blockIdx.x >= NSCAN) {              // C = Wh1[256:480]^T feat_aa_pe
    __shared__ float fe[224];
    __shared__ float red[256];
    int b8 = blockIdx.x - NSCAN;          // 0..7, 64 outputs each
    int t = threadIdx.x;
    int wtI = wtI_[0], mutI = mutI_[0];   // small non-negative; low word ok i32/i64
    if (t < 64) {
      float a = aa[wtI * 64 + t], b = aa[mutI * 64 + t];
      fe[t] = a; fe[64 + t] = b; fe[128 + t] = b - a;
    }
    int tgt = w.cnt[4];
    int pos = tgt > 511 ? 511 : tgt;
    if (t < 32) fe[192 + t] = pemb[pos * 32 + t];
    __syncthreads();
    int o = b8 * 64 + (t & 63), js = t >> 6;  // 4 j-slices x 56
    float v = 0.f;
    for (int j = js * 56; j < js * 56 + 56; ++j)
      v += fe[j] * Wh1[(256 + j) * 512 + o];
    red[t] = v;
    __syncthreads();
    if (t < 64) w.C[b8 * 64 + t] = red[t] + red[64 + t] + red[128 + t] + red[192 + t];
    return;
  }
  const int tgt = w.cnt[4];
  const bool is64 = w.cnt[3] != 0;
  const long long* ell = (const long long*)eiraw;
  int g = blockIdx.x * blockDim.x + threadIdx.x;
  const long gs = (long)NSCAN * 256;
  auto hit = [&](long e, int r_unused) {
    int r = is64 ? (int)ell[e] : eiraw[e];
    int i1 = atomicAdd(&w.cnt[0], 1);
    if (i1 < L1CAP) { w.l1r[i1] = r; w.l1w[i1] = ew[e]; }
  };
  if ((E & 1) == 0) {                     // vectorized: 2 edges per iteration
    long half = E >> 1;
    int2* ws2 = (int2*)w.wscol;
    if (is64) {
      const long2* c2 = (const long2*)(ell + E);
      for (long j = g; j < half; j += gs) {
        long2 v = c2[j];
        int c0 = (int)v.x, c1 = (int)v.y;
        ws2[j] = make_int2(c0, c1);
        if (c0 == tgt) hit(2 * j, 0);
        if (c1 == tgt) hit(2 * j + 1, 0);
      }
    } else {
      const int2* c2 = (const int2*)(eiraw + E);
      for (long j = g; j < half; j += gs) {
        int2 v = c2[j];
        ws2[j] = v;
        if (v.x == tgt) hit(2 * j, 0);
        if (v.y == tgt) hit(2 * j + 1, 0);
      }
    }
  } else {
    for (long e = g; e < E; e += gs) {
      int c = is64 ? (int)ell[(long)E + e] : eiraw[(long)E + e];
      w.wscol[e] = c;
      if (c == tgt) hit(e, 0);
    }
  }
  if (g == 0) {  // tgt's self loop (weight 1.0)
    int i1 = atomicAdd(&w.cnt[0], 1);
    if (i1 < L1CAP) { w.l1r[i1] = tgt; w.l1w[i1] = 1.0f; }
  }
}

// K3: 1024 blocks: per-block dedup -> s1 + LDS bitset; wscol int4 scan -> l2 + hash
__global__ void kpassB(WsPtrs w, const int* eiraw, const float* ew, int E) {
  __shared__ int      l1rS[L1CAP];
  __shared__ float    l1wS[L1CAP];
  __shared__ int      s1sL[SCAP];
  __shared__ unsigned bits[BITW];     // 16 KB
  __shared__ int      nsS;
  int tid = threadIdx.x;
  const bool is64 = w.cnt[3] != 0;
  const long long* ell = (const long long*)eiraw;
  int n1 = w.cnt[0]; if (n1 > L1CAP) n1 = L1CAP;
  for (int j = tid; j < BITW; j += 256) bits[j] = 0u;
  int ns = dedup_s1(w, n1, l1rS, l1wS, s1sL, &nsS, tid);
  for (int j = tid; j < ns; j += 256) {
    unsigned u = (unsigned)s1sL[j] & (BITW * 32 - 1);
    atomicOr(&bits[u >> 5], 1u << (u & 31));
    if (blockIdx.x == 0) {            // seed: S1 hash inserts + self-loop l2 edges
      int v = s1sL[j];
      hins(w, v);
      int idx = atomicAdd(&w.cnt[2], 1);
      if (idx < L2CAP) { w.l2r[idx] = v; w.l2s[idx] = j; w.l2w[idx] = 1.0f; }
    }
  }
  __syncthreads();
  int g = blockIdx.x * 256 + tid;
  const int gs = NB * 256;
  const int4* c4 = (const int4*)w.wscol;
  int nv = E >> 2;
  for (int j2 = g; j2 < nv; j2 += gs) {
    int4 vv = c4[j2];
    #pragma unroll
    for (int t = 0; t < 4; ++t) {
      int c = (t == 0) ? vv.x : (t == 1) ? vv.y : (t == 2) ? vv.z : vv.w;
      unsigned u = (unsigned)c & (BITW * 32 - 1);
      if (bits[u >> 5] & (1u << (u & 31))) {        // exact when N<=128K
        int s = -1;
        for (int j = 0; j < ns; ++j) if (s1sL[j] == c) { s = j; break; }
        if (s >= 0) {
          long e = 4L * j2 + t;
          int r = is64 ? (int)ell[e] : eiraw[e];
          int idx = atomicAdd(&w.cnt[2], 1);
          if (idx < L2CAP) { w.l2r[idx] = r; w.l2s[idx] = s; w.l2w[idx] = ew[e]; }
          hins(w, r);
        }
      }
    }
  }
  for (long e = 4L * nv + g; e < E; e += gs) {
    int c = w.wscol[e];
    int s = -1;
    for (int j = 0; j < ns; ++j) if (s1sL[j] == c) { s = j; break; }
    if (s >= 0) {
      int r = is64 ? (int)ell[e] : eiraw[e];
      int idx = atomicAdd(&w.cnt[2], 1);
      if (idx < L2CAP) { w.l2r[idx] = r; w.l2s[idx] = s; w.l2w[idx] = ew[e]; }
      hins(w, r);
    }
  }
}

// K4: 1024 blocks: LDS bitset from hash; wscol+ew scan -> deg atomics
__global__ void kpassC(WsPtrs w, const float* ew, int E) {
  __shared__ unsigned bits[BITW];
  int tid = threadIdx.x;
  for (int j = tid; j < BITW; j += 256) bits[j] = 0u;
  __syncthreads();
  for (int j = tid; j < HSZ; j += 256) {
    int u2 = w.hash[j];
    if (u2 >= 0) {
      unsigned u = (unsigned)u2 & (BITW * 32 - 1);
      atomicOr(&bits[u >> 5], 1u << (u & 31));
    }
  }
  __syncthreads();
  int g = blockIdx.x * 256 + tid;
  const int gs = NB * 256;
  const int4* c4 = (const int4*)w.wscol;
  int nv = E >> 2;
  for (int j2 = g; j2 < nv; j2 += gs) {
    int4 vv = c4[j2];
    #pragma unroll
    for (int t = 0; t < 4; ++t) {
      int c = (t == 0) ? vv.x : (t == 1) ? vv.y : (t == 2) ? vv.z : vv.w;
      unsigned u = (unsigned)c & (BITW * 32 - 1);
      if (bits[u >> 5] & (1u << (u & 31)))          // FP at N>128K: harmless extra add
        atomicAdd(&w.deg[c], ew[4L * j2 + t]);
    }
  }
  for (long e = 4L * nv + g; e < E; e += gs) {
    int c = w.wscol[e];
    unsigned u = (unsigned)c & (BITW * 32 - 1);
    if (bits[u >> 5] & (1u << (u & 31))) atomicAdd(&w.deg[c], ew[e]);
  }
}

// K5: 32 blocks, 4 joins; every weight matrix read once in aggregate.
__global__ void __launch_bounds__(256) ktail(
    WsPtrs w, const float* x, const float* W1, const float* b1,
    const float* W2, const float* b2, const float* mask,
    const float* Wh1, const float* bh1, const float* Wh2, const float* bh2,
    const float* Wh3, const float* bh3, float* out) {
  __shared__ int   l1rS[L1CAP];
  __shared__ float l1wS[L1CAP];
  __shared__ int   s1sL[SCAP];
  __shared__ int   nsS;
  __shared__ float xsL[64 * 129];     // 33 KB, padded stride kills 8-way conflict
  __shared__ float red[256];
  __shared__ float vecS[256];
  __shared__ float f1L[16];

  int tid = threadIdx.x, bid = blockIdx.x;
  const int tgt = w.cnt[4];
  int n1 = w.cnt[0]; if (n1 > L1CAP) n1 = L1CAP;
  int n2 = w.cnt[2]; if (n2 > L2CAP) n2 = L2CAP;
  int ns = dedup_s1(w, n1, l1rS, l1wS, s1sL, &nsS, tid);
  float dti = rsqrtf(w.deg[tgt]);
  float maskv = mask[tgt];

  // ---- 1a: edge-parallel gather -> global xsum (each block ~n2/64 edges) ----
  int grp = tid >> 7, lane = tid & 127;
  for (int i = bid * 2 + grp; i < n2; i += NTB * 2) {
    int s = w.l2s[i], r = w.l2r[i];
    float nrm = rsqrtf(w.deg[r]) * w.l2w[i] * rsqrtf(w.deg[s1sL[s]]);
    atomicAdd(&w.xsum[s * INDIM + lane], nrm * x[(long)r * INDIM + lane]);
  }
  join(&w.cnt[8], tid, NTB);

  // ---- 1b: one-pass W1 product; block owns outputs [bid*8, bid*8+8) ----
  int oi = tid & 7, vi = tid >> 3;
  int o = bid * 8 + oi;
  float h2acc = 0.f;
  for (int cb = 0; cb < ns; cb += 64) {
    int ce = ns - cb; if (ce > 64) ce = 64;
    for (int j = tid; j < ce * INDIM; j += 256)
      xsL[(j >> 7) * 129 + (j & 127)] =
        __hip_atomic_load(&w.xsum[cb * INDIM + j], __ATOMIC_RELAXED,
                          __HIP_MEMORY_SCOPE_AGENT);
    __syncthreads();
    for (int v = vi; v < ce; v += 32) {
      const float* xv = &xsL[v * 129];
      float h = b1[o];
      #pragma unroll 8
      for (int k = 0; k < INDIM; ++k) h += xv[k] * W1[k * HID + o];
      int node = s1sL[cb + v];
      float wsum = 0.f;                // sum of l1 weights with row==node
      for (int i = 0; i < n1; ++i) if (l1rS[i] == node) wsum += l1wS[i];
      h2acc += rsqrtf(w.deg[node]) * wsum * dti * fmaxf(h, 0.f);
    }
    __syncthreads();
  }
  red[tid] = h2acc;
  __syncthreads();
  if (tid < 8) {
    float t = 0.f;
    for (int q = 0; q < 32; ++q) t += red[q * 8 + tid];
    w.h2[bid * 8 + tid] = t;           // each output owned once: plain store
  }
  join(&w.cnt[9], tid, NTB);

  // ---- z slice: z[o] = relu(h2 @ W2 + b2)[o] * mask; W2 read once aggregate ----
  vecS[tid] = __hip_atomic_load(&w.h2[tid], __ATOMIC_RELAXED, __HIP_MEMORY_SCOPE_AGENT);
  __syncthreads();
  {
    float part = 0.f;
    for (int k = vi; k < HID; k += 32) part += vecS[k] * W2[k * HID + o];
    red[tid] = part;
  }
  __syncthreads();
  if (tid < 8) {
    float t = 0.f;
    for (int q = 0; q < 32; ++q) t += red[q * 8 + tid];
    w.z[bid * 8 + tid] = fmaxf(t + b2[bid * 8 + tid], 0.f) * maskv;
  }
  join(&w.cnt[10], tid, NTB);

  // ---- f1 slice (16 outs/block) + f2pre atomics ----
  vecS[tid] = __hip_atomic_load(&w.z[tid], __ATOMIC_RELAXED, __HIP_MEMORY_SCOPE_AGENT);
  __syncthreads();
  {
    int o0 = bid * 16, oo = o0 + (tid & 15), ks = tid >> 4;
    float v = 0.f;
    #pragma unroll 4
    for (int k = ks * 16; k < ks * 16 + 16; ++k) v += vecS[k] * Wh1[k * 512 + oo];
    red[tid] = v;
    __syncthreads();
    if (tid < 16) {
      float v2 = w.C[o0 + tid] + bh1[o0 + tid];
      for (int s2 = 0; s2 < 16; ++s2) v2 += red[s2 * 16 + tid];
      f1L[tid] = fmaxf(v2, 0.f);
    }
    __syncthreads();
    if (tid < 128) {
      float v3 = 0.f;
      #pragma unroll
      for (int j = 0; j < 16; ++j) v3 += f1L[j] * Wh2[(o0 + j) * 128 + tid];
      atomicAdd(&w.f2pre[tid], v3);
    }
  }
  __threadfence();
  __syncthreads();
  if (tid == 0)
    __hip_atomic_fetch_add(&w.cnt[11], 1, __ATOMIC_RELEASE, __HIP_MEMORY_SCOPE_AGENT);
  if (bid != 0) return;
  if (tid == 0)
    while (__hip_atomic_load(&w.cnt[11], __ATOMIC_ACQUIRE,
                             __HIP_MEMORY_SCOPE_AGENT) < NTB)
      __builtin_amdgcn_s_sleep(4);
  __syncthreads();

  // ---- out ----
  if (tid < 128)
    red[tid] = fmaxf(__hip_atomic_load(&w.f2pre[tid], __ATOMIC_RELAXED,
                                       __HIP_MEMORY_SCOPE_AGENT) + bh2[tid], 0.f)
               * Wh3[tid];
  __syncthreads();
  if (tid == 0) {
    float s = bh3[0];
    for (int k = 0; k < 128; ++k) s += red[k];
    out[0] = s;
  }
}

extern "C" void kernel_launch(void* const* d_in, const int* in_sizes, int n_in,
                              void* d_out, int out_size, void* d_ws, size_t ws_size,
                              hipStream_t stream) {
  const float* x    = (const float*)d_in[0];
  const int*   ei   = (const int*)d_in[1];
  const float* ew   = (const float*)d_in[2];
  const float* mask = (const float*)d_in[3];
  const int*   wtI  = (const int*)d_in[4];
  const int*   mutI = (const int*)d_in[5];
  const float* W1   = (const float*)d_in[6];
  const float* b1   = (const float*)d_in[7];
  const float* W2   = (const float*)d_in[8];
  const float* b2   = (const float*)d_in[9];
  const float* aa   = (const float*)d_in[10];
  const float* pemb = (const float*)d_in[11];
  const float* Wh1  = (const float*)d_in[12];
  const float* bh1  = (const float*)d_in[13];
  const float* Wh2  = (const float*)d_in[14];
  const float* bh2  = (const float*)d_in[15];
  const float* Wh3  = (const float*)d_in[16];
  const float* bh3  = (const float*)d_in[17];
  float* out = (float*)d_out;
  const int N = in_sizes[3];   // mut_mask length
  const int E = in_sizes[2];   // edge_weight length

  char* q = (char*)d_ws;
  auto take = [&](size_t bytes) -> char* {
    char* r = q; q += (bytes + 255) & ~(size_t)255; return r;
  };
  WsPtrs w;
  w.cnt   = (int*)take(64);
  w.deg   = (float*)take((size_t)N * 4);
  w.hash  = (int*)take(HSZ * 4);
  w.l1r   = (int*)take(L1CAP * 4);
  w.l1w   = (float*)take(L1CAP * 4);
  w.l2r   = (int*)take(L2CAP * 4);
  w.l2s   = (int*)take(L2CAP * 4);
  w.l2w   = (float*)take(L2CAP * 4);
  w.wscol = (int*)take((size_t)E * 4);
  w.xsum  = (float*)take((size_t)SCAP * INDIM * 4);
  w.h2    = (float*)take(HID * 4);
  w.C     = (float*)take(512 * 4);
  w.z     = (float*)take(256 * 4);
  w.f2pre = (float*)take(128 * 4);

  kinit  <<<64, 256, 0, stream>>>(w, ei, mask, N, E);
  kpassA <<<NSCAN + 16, 256, 0, stream>>>(w, ei, ew, wtI, mutI, aa, pemb, Wh1,
                                          W1, W2, Wh2, E);
  kpassB <<<NB, 256, 0, stream>>>(w, ei, ew, E);
  kpassC <<<NB, 256, 0, stream>>>(w, ew, E);
  ktail  <<<NTB, 256, 0, stream>>>(w, x, W1, b1, W2, b2, mask,
                                   Wh1, bh1, Wh2, bh2, Wh3, bh3, out);
}

// Round 8
// 202.091 us; speedup vs baseline: 2.2027x; 1.0070x over previous
//
#include <hip/hip_runtime.h>

// Sparse 2-hop GCN slice: output depends only on h2[tgt], tgt = argmax(mut_mask).
// R12: R11 skeleton; ktail sync rewritten. Diagnosis: R11's join did threadfence
// (L2 wb) + RELEASE add (2nd wb) + ACQUIRE poll (L2 INVALIDATE PER POLL ITER) ->
// ~90% stall. Fix: one RELEASE add, RELAXED poll, no fence/acquire (all cross-block
// reads use agent-RELAXED atomic loads = coherent-point reads). Weight slices are
// prefetched into LDS before each join so L3 latency hides under the wait.
//   kinit  | kpassA (scan+C-precompute+warm) | kpassB | kpassC | ktail (4 joins)

#define SCAP   512      // cap on |S1|; expected ~17
#define L1CAP  512      // cap on edges into tgt; expected ~17
#define L2CAP  16384    // cap on edges into S1; expected ~300
#define HID    256
#define INDIM  128
#define HSZ    4096     // deg-needed hash (power of 2; ~320 entries expected)
#define BITW   4096     // LDS bitset words (131072 bits, power of 2)
#define NSCAN  2048     // scanning blocks in kpassA
#define NB     1024     // kpassB/kpassC grids
#define NTB    32       // ktail grid

struct WsPtrs {
  int* cnt;     // [0]=n1 [2]=n2 [3]=is64 [4]=tgt [8..11]=join ctrs [15]=dummy
  float* deg;   // [N] lazily initialized via hash insert
  int* hash;    // [HSZ] open-addressing set of deg-needed nodes (-1 empty)
  int* l1r; float* l1w;            // edges into tgt
  int* l2r; int* l2s; float* l2w;  // edges into S1
  int* wscol;   // [E] col as int32
  float* xsum;  // [SCAP*INDIM] per-slot normalized x sums
  float* h2;    // [HID]
  float* C;     // [512] aa/pos part of head layer 1
  float* z;     // [256]
  float* f2pre; // [128]
};

// K1: counters + hash clear + xsum/f2pre zero + argmax(one-hot) + is64 detect
__global__ void kinit(WsPtrs w, const int* eiraw, const float* mask, int N, int E) {
  int g = blockIdx.x * blockDim.x + threadIdx.x;
  int gs = gridDim.x * blockDim.x;
  for (int j = g; j < N; j += gs)
    if (mask[j] > 0.f) w.cnt[4] = j;   // one-hot: exactly one thread fires
  for (int j = g; j < HSZ; j += gs) w.hash[j] = -1;
  float4* xz = (float4*)w.xsum;
  for (int j = g; j < SCAP * INDIM / 4; j += gs) xz[j] = make_float4(0.f, 0.f, 0.f, 0.f);
  if (g < HID) w.h2[g] = 0.f;
  if (g < 128) w.f2pre[g] = 0.f;
  if (g < 3) w.cnt[g] = 0;
  if (g >= 8 && g < 16) w.cnt[g] = 0;
  if (g == 3) {
    int bad = 0;
    long step = E / 20; if (step < 1) step = 1;
    #pragma unroll
    for (int j = 1; j <= 16; ++j) {
      long idx = (long)j * step;
      if (idx < E) bad |= (eiraw[2 * idx + 1] != 0);  // ids < 2^31 -> hi word 0
    }
    w.cnt[3] = bad ? 0 : 1;
  }
}

// open-address insert; winner lazily inits deg[u]=1.0 (self-loop weight)
__device__ __forceinline__ void hins(WsPtrs& w, int u) {
  unsigned h = ((unsigned)u * 2654435761u) >> 20;   // 12-bit slot
  for (;;) {
    int cur = __hip_atomic_load(&w.hash[h], __ATOMIC_RELAXED, __HIP_MEMORY_SCOPE_AGENT);
    if (cur == u) return;
    if (cur == -1) {
      int old = atomicCAS(&w.hash[h], -1, u);
      if (old == -1) { w.deg[u] = 1.0f; return; }
      if (old == u) return;
    }
    h = (h + 1) & (HSZ - 1);
  }
}

// cheap device-scope join: ONE release add (flushes this block's plain stores),
// RELAXED poll (no per-iteration cache invalidate). Consumers must read shared
// data via agent-RELAXED atomic loads (coherent-point reads) -- they do.
__device__ __forceinline__ void join(int* ctr, int tid, int target) {
  __syncthreads();
  if (tid == 0) {
    __hip_atomic_fetch_add(ctr, 1, __ATOMIC_RELEASE, __HIP_MEMORY_SCOPE_AGENT);
    while (__hip_atomic_load(ctr, __ATOMIC_RELAXED, __HIP_MEMORY_SCOPE_AGENT) < target)
      __builtin_amdgcn_s_sleep(8);
  }
  __syncthreads();
}

__device__ __forceinline__ float warmf4(const float* base, int nf4, int tid) {
  const float4* p = (const float4*)base;
  float a = 0.f;
  for (int i = tid; i < nf4; i += 256) { float4 v = p[i]; a += v.x + v.y + v.z + v.w; }
  return a;
}

// builds the identical dedup'd s1 list in this block's LDS; returns ns
__device__ __forceinline__ int dedup_s1(WsPtrs& w, int n1, int* l1rS, float* l1wS,
                                        int* s1sL, int* nsS, int tid) {
  for (int i = tid; i < n1; i += 256) { l1rS[i] = w.l1r[i]; l1wS[i] = w.l1w[i]; }
  __syncthreads();
  if (tid == 0) {                     // n1 ~17 -> trivial serial dedup
    int ns = 0;
    for (int i = 0; i < n1; ++i) {
      int v = l1rS[i]; bool seen = false;
      for (int j = 0; j < ns; ++j) if (s1sL[j] == v) { seen = true; break; }
      if (!seen && ns < SCAP) s1sL[ns++] = v;
    }
    *nsS = ns;
  }
  __syncthreads();
  return *nsS;
}

// K2: scan col -> wscol + L1 edges (2 edges/iter). Extra blocks: C-precompute + warm.
__global__ void kpassA(WsPtrs w, const int* eiraw, const float* ew,
                       const int* wtI_, const int* mutI_,
                       const float* aa, const float* pemb, const float* Wh1,
                       const float* W1, const float* W2, const float* Wh2, int E) {
  if (blockIdx.x >= NSCAN + 8) {          // 8 warm blocks: stream 1.2MB into L3
    int b8 = blockIdx.x - (NSCAN + 8);
    int tid = threadIdx.x;
    float wa = warmf4(W1  + b8 * 4096, 1024, tid)     //  32768 floats total
             + warmf4(W2  + b8 * 8192, 2048, tid)     //  65536
             + warmf4(Wh1 + b8 * 16384, 4096, tid)    // rows 0..255 = 131072
             + warmf4(Wh2 + b8 * 8192, 2048, tid);    //  65536
    if (wa == 1.2345e38f) w.cnt[15] = 1;  // keep loads live; never true
    return;
  }
  if (blockIdx.x >= NSCAN) {              // C = Wh1[256:480]^T feat_aa_pe
    __shared__ float fe[224];
    __shared__ float red[256];
    int b8 = blockIdx.x - NSCAN;          // 0..7, 64 outputs each
    int t = threadIdx.x;
    int wtI = wtI_[0], mutI = mutI_[0];   // small non-negative; low word ok i32/i64
    if (t < 64) {
      float a = aa[wtI * 64 + t], b = aa[mutI * 64 + t];
      fe[t] = a; fe[64 + t] = b; fe[128 + t] = b - a;
    }
    int tgt = w.cnt[4];
    int pos = tgt > 511 ? 511 : tgt;
    if (t < 32) fe[192 + t] = pemb[pos * 32 + t];
    __syncthreads();
    int o = b8 * 64 + (t & 63), js = t >> 6;  // 4 j-slices x 56
    float v = 0.f;
    for (int j = js * 56; j < js * 56 + 56; ++j)
      v += fe[j] * Wh1[(256 + j) * 512 + o];
    red[t] = v;
    __syncthreads();
    if (t < 64) w.C[b8 * 64 + t] = red[t] + red[64 + t] + red[128 + t] + red[192 + t];
    return;
  }
  const int tgt = w.cnt[4];
  const bool is64 = w.cnt[3] != 0;
  const long long* ell = (const long long*)eiraw;
  int g = blockIdx.x * blockDim.x + threadIdx.x;
  const long gs = (long)NSCAN * 256;
  auto hit = [&](long e) {
    int r = is64 ? (int)ell[e] : eiraw[e];
    int i1 = atomicAdd(&w.cnt[0], 1);
    if (i1 < L1CAP) { w.l1r[i1] = r; w.l1w[i1] = ew[e]; }
  };
  if ((E & 1) == 0) {                     // vectorized: 2 edges per iteration
    long half = E >> 1;
    int2* ws2 = (int2*)w.wscol;
    if (is64) {
      const long2* c2 = (const long2*)(ell + E);
      for (long j = g; j < half; j += gs) {
        long2 v = c2[j];
        int c0 = (int)v.x, c1 = (int)v.y;
        ws2[j] = make_int2(c0, c1);
        if (c0 == tgt) hit(2 * j);
        if (c1 == tgt) hit(2 * j + 1);
      }
    } else {
      const int2* c2 = (const int2*)(eiraw + E);
      for (long j = g; j < half; j += gs) {
        int2 v = c2[j];
        ws2[j] = v;
        if (v.x == tgt) hit(2 * j);
        if (v.y == tgt) hit(2 * j + 1);
      }
    }
  } else {
    for (long e = g; e < E; e += gs) {
      int c = is64 ? (int)ell[(long)E + e] : eiraw[(long)E + e];
      w.wscol[e] = c;
      if (c == tgt) hit(e);
    }
  }
  if (g == 0) {  // tgt's self loop (weight 1.0)
    int i1 = atomicAdd(&w.cnt[0], 1);
    if (i1 < L1CAP) { w.l1r[i1] = tgt; w.l1w[i1] = 1.0f; }
  }
}

// K3: 1024 blocks: per-block dedup -> s1 + LDS bitset; wscol int4 scan -> l2 + hash
__global__ void kpassB(WsPtrs w, const int* eiraw, const float* ew, int E) {
  __shared__ int      l1rS[L1CAP];
  __shared__ float    l1wS[L1CAP];
  __shared__ int      s1sL[SCAP];
  __shared__ unsigned bits[BITW];     // 16 KB
  __shared__ int      nsS;
  int tid = threadIdx.x;
  const bool is64 = w.cnt[3] != 0;
  const long long* ell = (const long long*)eiraw;
  int n1 = w.cnt[0]; if (n1 > L1CAP) n1 = L1CAP;
  for (int j = tid; j < BITW; j += 256) bits[j] = 0u;
  int ns = dedup_s1(w, n1, l1rS, l1wS, s1sL, &nsS, tid);
  for (int j = tid; j < ns; j += 256) {
    unsigned u = (unsigned)s1sL[j] & (BITW * 32 - 1);
    atomicOr(&bits[u >> 5], 1u << (u & 31));
    if (blockIdx.x == 0) {            // seed: S1 hash inserts + self-loop l2 edges
      int v = s1sL[j];
      hins(w, v);
      int idx = atomicAdd(&w.cnt[2], 1);
      if (idx < L2CAP) { w.l2r[idx] = v; w.l2s[idx] = j; w.l2w[idx] = 1.0f; }
    }
  }
  __syncthreads();
  int g = blockIdx.x * 256 + tid;
  const int gs = NB * 256;
  const int4* c4 = (const int4*)w.wscol;
  int nv = E >> 2;
  for (int j2 = g; j2 < nv; j2 += gs) {
    int4 vv = c4[j2];
    #pragma unroll
    for (int t = 0; t < 4; ++t) {
      int c = (t == 0) ? vv.x : (t == 1) ? vv.y : (t == 2) ? vv.z : vv.w;
      unsigned u = (unsigned)c & (BITW * 32 - 1);
      if (bits[u >> 5] & (1u << (u & 31))) {        // exact when N<=128K
        int s = -1;
        for (int j = 0; j < ns; ++j) if (s1sL[j] == c) { s = j; break; }
        if (s >= 0) {
          long e = 4L * j2 + t;
          int r = is64 ? (int)ell[e] : eiraw[e];
          int idx = atomicAdd(&w.cnt[2], 1);
          if (idx < L2CAP) { w.l2r[idx] = r; w.l2s[idx] = s; w.l2w[idx] = ew[e]; }
          hins(w, r);
        }
      }
    }
  }
  for (long e = 4L * nv + g; e < E; e += gs) {
    int c = w.wscol[e];
    int s = -1;
    for (int j = 0; j < ns; ++j) if (s1sL[j] == c) { s = j; break; }
    if (s >= 0) {
      int r = is64 ? (int)ell[e] : eiraw[e];
      int idx = atomicAdd(&w.cnt[2], 1);
      if (idx < L2CAP) { w.l2r[idx] = r; w.l2s[idx] = s; w.l2w[idx] = ew[e]; }
      hins(w, r);
    }
  }
}

// K4: 1024 blocks: LDS bitset from hash; wscol+ew scan -> deg atomics
__global__ void kpassC(WsPtrs w, const float* ew, int E) {
  __shared__ unsigned bits[BITW];
  int tid = threadIdx.x;
  for (int j = tid; j < BITW; j += 256) bits[j] = 0u;
  __syncthreads();
  for (int j = tid; j < HSZ; j += 256) {
    int u2 = w.hash[j];
    if (u2 >= 0) {
      unsigned u = (unsigned)u2 & (BITW * 32 - 1);
      atomicOr(&bits[u >> 5], 1u << (u & 31));
    }
  }
  __syncthreads();
  int g = blockIdx.x * 256 + tid;
  const int gs = NB * 256;
  const int4* c4 = (const int4*)w.wscol;
  int nv = E >> 2;
  for (int j2 = g; j2 < nv; j2 += gs) {
    int4 vv = c4[j2];
    #pragma unroll
    for (int t = 0; t < 4; ++t) {
      int c = (t == 0) ? vv.x : (t == 1) ? vv.y : (t == 2) ? vv.z : vv.w;
      unsigned u = (unsigned)c & (BITW * 32 - 1);
      if (bits[u >> 5] & (1u << (u & 31)))          // FP at N>128K: harmless extra add
        atomicAdd(&w.deg[c], ew[4L * j2 + t]);
    }
  }
  for (long e = 4L * nv + g; e < E; e += gs) {
    int c = w.wscol[e];
    unsigned u = (unsigned)c & (BITW * 32 - 1);
    if (bits[u >> 5] & (1u << (u & 31))) atomicAdd(&w.deg[c], ew[e]);
  }
}

// K5: 32 blocks, 4 cheap joins; weight slices prefetched to LDS under join waits.
__global__ void __launch_bounds__(256) ktail(
    WsPtrs w, const float* x, const float* W1, const float* b1,
    const float* W2, const float* b2, const float* mask,
    const float* Wh1, const float* bh1, const float* Wh2, const float* bh2,
    const float* Wh3, const float* bh3, float* out) {
  __shared__ int   l1rS[L1CAP];
  __shared__ float l1wS[L1CAP];
  __shared__ int   s1sL[SCAP];
  __shared__ int   nsS;
  __shared__ float xsL[32 * 129];     // 16.5 KB padded (32-slot chunks)
  __shared__ float red[256];
  __shared__ float vecS[256];
  __shared__ float f1L[16];
  __shared__ float w1S[INDIM * 8];    //  4 KB: W1[:, bid*8..+8)
  __shared__ float w2S[HID * 8];      //  8 KB: W2[:, bid*8..+8)
  __shared__ float wh1S[256 * 16];    // 16 KB: Wh1[0:256, bid*16..+16)
  __shared__ float wh2S[16 * 128];    //  8 KB: Wh2[bid*16..+16, :]

  int tid = threadIdx.x, bid = blockIdx.x;
  const int tgt = w.cnt[4];
  int n1 = w.cnt[0]; if (n1 > L1CAP) n1 = L1CAP;
  int n2 = w.cnt[2]; if (n2 > L2CAP) n2 = L2CAP;
  int ns = dedup_s1(w, n1, l1rS, l1wS, s1sL, &nsS, tid);
  float dti = rsqrtf(w.deg[tgt]);
  float maskv = mask[tgt];

  // ---- prefetch W1/W2 slices to LDS (hidden under gather + join1) ----
  for (int j = tid; j < INDIM * 8; j += 256)
    w1S[j] = W1[(j >> 3) * HID + bid * 8 + (j & 7)];
  for (int j = tid; j < HID * 8; j += 256)
    w2S[j] = W2[(j >> 3) * HID + bid * 8 + (j & 7)];

  // ---- 1a: edge-parallel gather -> global xsum ----
  int grp = tid >> 7, lane = tid & 127;
  for (int i = bid * 2 + grp; i < n2; i += NTB * 2) {
    int s = w.l2s[i], r = w.l2r[i];
    float nrm = rsqrtf(w.deg[r]) * w.l2w[i] * rsqrtf(w.deg[s1sL[s]]);
    atomicAdd(&w.xsum[s * INDIM + lane], nrm * x[(long)r * INDIM + lane]);
  }
  join(&w.cnt[8], tid, NTB);

  // ---- 1b: one-pass W1 product; block owns h2 outputs [bid*8, bid*8+8) ----
  int oi = tid & 7, vi = tid >> 3;
  int o = bid * 8 + oi;
  float h2acc = 0.f;
  for (int cb = 0; cb < ns; cb += 32) {
    int ce = ns - cb; if (ce > 32) ce = 32;
    for (int j = tid; j < ce * INDIM; j += 256)
      xsL[(j >> 7) * 129 + (j & 127)] =
        __hip_atomic_load(&w.xsum[cb * INDIM + j], __ATOMIC_RELAXED,
                          __HIP_MEMORY_SCOPE_AGENT);
    __syncthreads();
    if (vi < ce) {
      const float* xv = &xsL[vi * 129];
      float h = b1[o];
      #pragma unroll 8
      for (int k = 0; k < INDIM; ++k) h += xv[k] * w1S[k * 8 + oi];
      int node = s1sL[cb + vi];
      float wsum = 0.f;                // sum of l1 weights with row==node
      for (int i = 0; i < n1; ++i) if (l1rS[i] == node) wsum += l1wS[i];
      h2acc += rsqrtf(w.deg[node]) * wsum * dti * fmaxf(h, 0.f);
    }
    __syncthreads();
  }
  red[tid] = h2acc;
  // ---- prefetch Wh1/Wh2 slices (hidden under join2/join3 waits) ----
  for (int j = tid; j < 256 * 16; j += 256)
    wh1S[j] = Wh1[(j >> 4) * 512 + bid * 16 + (j & 15)];
  for (int j = tid; j < 16 * 128; j += 256)
    wh2S[j] = Wh2[(bid * 16 + (j >> 7)) * 128 + (j & 127)];
  __syncthreads();
  if (tid < 8) {
    float t = 0.f;
    for (int q = 0; q < 32; ++q) t += red[q * 8 + tid];
    w.h2[bid * 8 + tid] = t;           // plain store; join2's release flushes
  }
  join(&w.cnt[9], tid, NTB);

  // ---- z slice: z[o] = relu(h2 @ W2 + b2)[o] * mask ----
  vecS[tid] = __hip_atomic_load(&w.h2[tid], __ATOMIC_RELAXED, __HIP_MEMORY_SCOPE_AGENT);
  __syncthreads();
  {
    float part = 0.f;
    for (int k = vi; k < HID; k += 32) part += vecS[k] * w2S[k * 8 + oi];
    red[tid] = part;
  }
  __syncthreads();
  if (tid < 8) {
    float t = 0.f;
    for (int q = 0; q < 32; ++q) t += red[q * 8 + tid];
    w.z[bid * 8 + tid] = fmaxf(t + b2[bid * 8 + tid], 0.f) * maskv;
  }
  join(&w.cnt[10], tid, NTB);

  // ---- f1 slice (16 outs/block) + f2pre atomics ----
  vecS[tid] = __hip_atomic_load(&w.z[tid], __ATOMIC_RELAXED, __HIP_MEMORY_SCOPE_AGENT);
  __syncthreads();
  {
    int o0 = bid * 16, oo = tid & 15, ks = tid >> 4;
    float v = 0.f;
    #pragma unroll 4
    for (int k = ks * 16; k < ks * 16 + 16; ++k) v += vecS[k] * wh1S[k * 16 + oo];
    red[tid] = v;
    __syncthreads();
    if (tid < 16) {
      float v2 = w.C[o0 + tid] + bh1[o0 + tid];
      for (int s2 = 0; s2 < 16; ++s2) v2 += red[s2 * 16 + tid];
      f1L[tid] = fmaxf(v2, 0.f);
    }
    __syncthreads();
    if (tid < 128) {
      float v3 = 0.f;
      #pragma unroll
      for (int j = 0; j < 16; ++j) v3 += f1L[j] * wh2S[j * 128 + tid];
      atomicAdd(&w.f2pre[tid], v3);
    }
  }
  // final signal; only block 0 polls and finishes
  __syncthreads();
  if (tid == 0)
    __hip_atomic_fetch_add(&w.cnt[11], 1, __ATOMIC_RELEASE, __HIP_MEMORY_SCOPE_AGENT);
  if (bid != 0) return;
  if (tid == 0)
    while (__hip_atomic_load(&w.cnt[11], __ATOMIC_RELAXED,
                             __HIP_MEMORY_SCOPE_AGENT) < NTB)
      __builtin_amdgcn_s_sleep(8);
  __syncthreads();

  // ---- out ----
  if (tid < 128)
    red[tid] = fmaxf(__hip_atomic_load(&w.f2pre[tid], __ATOMIC_RELAXED,
                                       __HIP_MEMORY_SCOPE_AGENT) + bh2[tid], 0.f)
               * Wh3[tid];
  __syncthreads();
  if (tid == 0) {
    float s = bh3[0];
    for (int k = 0; k < 128; ++k) s += red[k];
    out[0] = s;
  }
}

extern "C" void kernel_launch(void* const* d_in, const int* in_sizes, int n_in,
                              void* d_out, int out_size, void* d_ws, size_t ws_size,
                              hipStream_t stream) {
  const float* x    = (const float*)d_in[0];
  const int*   ei   = (const int*)d_in[1];
  const float* ew   = (const float*)d_in[2];
  const float* mask = (const float*)d_in[3];
  const int*   wtI  = (const int*)d_in[4];
  const int*   mutI = (const int*)d_in[5];
  const float* W1   = (const float*)d_in[6];
  const float* b1   = (const float*)d_in[7];
  const float* W2   = (const float*)d_in[8];
  const float* b2   = (const float*)d_in[9];
  const float* aa   = (const float*)d_in[10];
  const float* pemb = (const float*)d_in[11];
  const float* Wh1  = (const float*)d_in[12];
  const float* bh1  = (const float*)d_in[13];
  const float* Wh2  = (const float*)d_in[14];
  const float* bh2  = (const float*)d_in[15];
  const float* Wh3  = (const float*)d_in[16];
  const float* bh3  = (const float*)d_in[17];
  float* out = (float*)d_out;
  const int N = in_sizes[3];   // mut_mask length
  const int E = in_sizes[2];   // edge_weight length

  char* q = (char*)d_ws;
  auto take = [&](size_t bytes) -> char* {
    char* r = q; q += (bytes + 255) & ~(size_t)255; return r;
  };
  WsPtrs w;
  w.cnt   = (int*)take(64);
  w.deg   = (float*)take((size_t)N * 4);
  w.hash  = (int*)take(HSZ * 4);
  w.l1r   = (int*)take(L1CAP * 4);
  w.l1w   = (float*)take(L1CAP * 4);
  w.l2r   = (int*)take(L2CAP * 4);
  w.l2s   = (int*)take(L2CAP * 4);
  w.l2w   = (float*)take(L2CAP * 4);
  w.wscol = (int*)take((size_t)E * 4);
  w.xsum  = (float*)take((size_t)SCAP * INDIM * 4);
  w.h2    = (float*)take(HID * 4);
  w.C     = (float*)take(512 * 4);
  w.z     = (float*)take(256 * 4);
  w.f2pre = (float*)take(128 * 4);

  kinit  <<<64, 256, 0, stream>>>(w, ei, mask, N, E);
  kpassA <<<NSCAN + 16, 256, 0, stream>>>(w, ei, ew, wtI, mutI, aa, pemb, Wh1,
                                          W1, W2, Wh2, E);
  kpassB <<<NB, 256, 0, stream>>>(w, ei, ew, E);
  kpassC <<<NB, 256, 0, stream>>>(w, ew, E);
  ktail  <<<NTB, 256, 0, stream>>>(w, x, W1, b1, W2, b2, mask,
                                   Wh1, bh1, Wh2, bh2, Wh3, bh3, out);
}